// Round 9
// baseline (1261.076 us; speedup 1.0000x reference)
//
#include <hip/hip_runtime.h>
#include <float.h>
#include <math.h>

// ---------------------------------------------------------------------------
// SSFE_Net pipeline on MI355X. B=16, N=2048.
// R7: LDS-buffered FPS outputs + DPP/ballot topk. 450us fused, knn-limited.
// R8: de-stage knn refs (L1/L2-resident, 24KB/batch) -> no LDS staging, no
//     barrier in knn; fused-kernel LDS 42.5KB -> ~9.5KB => 3 -> 5 blocks/CU
//     (20 waves). FPS coords live in registers (8/thread); winner coords
//     travel through the merge table (no centroid memory read).
// ---------------------------------------------------------------------------

static constexpr int B_   = 16;
static constexpr int N_   = 2048;
static constexpr int NP1  = 512;
static constexpr int NP2  = 256;
static constexpr int KG   = 20;
static constexpr int NSAMP= 32;
static constexpr int CHQ  = 256;   // query chunk for feature-knn distance matrix

// workspace offsets (in float elements)
static constexpr long OFF_FT   = 0;
static constexpr long OFF_SQ   = OFF_FT   + (long)B_*N_*64;
static constexpr long OFF_BIG  = OFF_SQ   + (long)B_*N_;          // D chunk / P / Q0 (aliased)
static constexpr long OFF_IDXG = OFF_BIG  + (long)B_*N_*256;
static constexpr long OFF_IDXF = OFF_IDXG + (long)B_*N_*KG;
static constexpr long OFF_OUTF = OFF_IDXF + (long)B_*N_*KG;
static constexpr long OFF_FPS1 = OFF_OUTF + (long)B_*N_*64;
static constexpr long OFF_NX1  = OFF_FPS1 + (long)B_*NP1;
static constexpr long OFF_IDX1 = OFF_NX1  + (long)B_*NP1*3;
static constexpr long OFF_F0T  = OFF_IDX1 + (long)B_*NP1*NSAMP;
static constexpr long OFF_FPS2 = OFF_F0T  + (long)B_*NP1*128;
static constexpr long OFF_NX2  = OFF_FPS2 + (long)B_*NP2;
static constexpr long OFF_IDX2 = OFF_NX2  + (long)B_*NP2*3;
static constexpr long OFF_Q1   = OFF_IDX2 + (long)B_*NP2*NSAMP;
static constexpr long OFF_V    = OFF_Q1   + (long)B_*NP1*512;
static constexpr long OFF_WPP  = OFF_V    + (long)B_*NP2*1280;
static constexpr long OFF_WPQ0 = OFF_WPP  + 256*64;
static constexpr long OFF_WPQ1 = OFF_WPQ0 + 256*64;
static constexpr long OFF_WFT  = OFF_WPQ1 + 512*128;
static constexpr long OFF_SC   = OFF_WFT  + 128*64;

// SC (bn scale/shift) sub-offsets
static constexpr int SC_S1=0, SC_T1=64, SC_SGEO=128, SC_TGEO=192, SC_SFEAT=256, SC_TFEAT=320,
   SC_SFUSE=384, SC_TFUSE=448, SC_SGL0=512, SC_TGL0=640, SC_SGL1=768, SC_TGL1=1024,
   SC_S2=1280, SC_T2=2304, SC_SF=3328, SC_TF=3840;

__device__ __forceinline__ float lrelu_(float x) { return x >= 0.0f ? x : 0.2f * x; }

// DPP-accelerated wave64 max (value only; all lanes end with the max).
template<int CTRL>
__device__ __forceinline__ float dpp_max(float v) {
    int o = __builtin_amdgcn_update_dpp(0, __float_as_int(v), CTRL, 0xF, 0xF, true);
    return fmaxf(v, __int_as_float(o));
}
__device__ __forceinline__ float wave_max64(float v) {
    v = dpp_max<0xB1>(v);    // quad_perm(1,0,3,2)
    v = dpp_max<0x4E>(v);    // quad_perm(2,3,0,1)
    v = dpp_max<0x141>(v);   // row_half_mirror
    v = dpp_max<0x140>(v);   // row_mirror
    v = fmaxf(v, __shfl_xor(v, 16));
    v = fmaxf(v, __shfl_xor(v, 32));
    return v;
}

// DPP-accelerated wave64 unsigned min (value only).
template<int CTRL>
__device__ __forceinline__ unsigned dpp_minu(unsigned x) {
    unsigned o = (unsigned)__builtin_amdgcn_update_dpp(0, (int)x, CTRL, 0xF, 0xF, true);
    return o < x ? o : x;
}
__device__ __forceinline__ unsigned wave_minu(unsigned x) {
    x = dpp_minu<0xB1>(x);
    x = dpp_minu<0x4E>(x);
    x = dpp_minu<0x141>(x);
    x = dpp_minu<0x140>(x);
    { unsigned o = (unsigned)__shfl_xor((int)x, 16); x = o < x ? o : x; }
    { unsigned o = (unsigned)__shfl_xor((int)x, 32); x = o < x ? o : x; }
    return x;
}

// monotone float -> sortable u32 (handles negative values from rounding)
__device__ __forceinline__ unsigned sortable_(float f) {
    unsigned u = __float_as_uint(f);
    return u ^ ((unsigned)((int)u >> 31) | 0x80000000u);
}

// ---------------------------------------------------------------------------
// prep: bn scale/shift + packed weight matrices
// ---------------------------------------------------------------------------
__global__ void k_prep(const float* __restrict__ bn1, const float* __restrict__ bn2,
                       const float* __restrict__ geow, const float* __restrict__ geobn,
                       const float* __restrict__ featw, const float* __restrict__ featbn,
                       const float* __restrict__ fusew, const float* __restrict__ fusebn,
                       const float* __restrict__ gl0w, const float* __restrict__ gl0bn,
                       const float* __restrict__ gl1w, const float* __restrict__ gl1bn,
                       const float* __restrict__ bnfp, float* __restrict__ ws)
{
    const int tid = blockIdx.x * blockDim.x + threadIdx.x;
    const int nt  = gridDim.x * blockDim.x;
    float* sc = ws + OFF_SC;

    {
        const float* ps[8]  = {bn1, geobn, featbn, fusebn, gl0bn, gl1bn, bn2, bnfp};
        const int    ch[8]  = {64, 64, 64, 64, 128, 256, 1024, 512};
        const int    so[8]  = {SC_S1, SC_SGEO, SC_SFEAT, SC_SFUSE, SC_SGL0, SC_SGL1, SC_S2, SC_SF};
        const int    to[8]  = {SC_T1, SC_TGEO, SC_TFEAT, SC_TFUSE, SC_TGL0, SC_TGL1, SC_T2, SC_TF};
        for (int g = 0; g < 8; g++) {
            const float* p = ps[g]; int C = ch[g];
            for (int i = tid; i < C; i += nt) {
                float gg = p[i], bb = p[C+i], mm = p[2*C+i], vv = p[3*C+i];
                float s = gg * (1.0f / sqrtf(vv + 1e-5f));
                sc[so[g] + i] = s;
                sc[to[g] + i] = bb - mm * s;
            }
        }
    }
    for (int j = tid; j < 256*64; j += nt) {
        int o = j >> 6, c = j & 63; float v;
        if      (o < 64)  v = geow[o*128 + c];
        else if (o < 128) v = geow[(o-64)*128 + 64 + c];
        else if (o < 192) v = featw[(o-128)*128 + c];
        else              v = featw[(o-192)*128 + 64 + c];
        ws[OFF_WPP + j] = v;
    }
    for (int j = tid; j < 256*64; j += nt) {
        int o = j >> 6, c = j & 63; float v;
        if (o < 128) v = gl0w[o*128 + c];
        else         v = gl0w[(o-128)*128 + 64 + c] - gl0w[(o-128)*128 + c];
        ws[OFF_WPQ0 + j] = v;
    }
    for (int j = tid; j < 512*128; j += nt) {
        int o = j >> 7, c = j & 127; float v;
        if (o < 256) v = gl1w[o*256 + c];
        else         v = gl1w[(o-256)*256 + 128 + c] - gl1w[(o-256)*256 + c];
        ws[OFF_WPQ1 + j] = v;
    }
    for (int j = tid; j < 128*64; j += nt) {
        int c = j >> 6, o = j & 63;
        ws[OFF_WFT + j] = fusew[o*128 + c];
    }
}

// ---------------------------------------------------------------------------
// f_t[b][n][o] = relu(bn1(sum_c w1[o][c]*x[b][c][n])) ; sq[b][n] = sum_o f^2
// ---------------------------------------------------------------------------
__global__ void __launch_bounds__(256) k_feat0(const float* __restrict__ x,
                                               const float* __restrict__ w1,
                                               const float* __restrict__ sc,
                                               float* __restrict__ ft, float* __restrict__ sq)
{
    const int t = threadIdx.x, lane = t & 63, w = t >> 6;
    const int pid = blockIdx.x*4 + w;
    const int b = pid >> 11, n = pid & (N_-1);
    const float* xb = x + (long)b*6*N_ + n;
    float acc = 0.0f;
    #pragma unroll
    for (int c = 0; c < 6; c++) acc += w1[lane*6 + c] * xb[(long)c*N_];
    float val = fmaxf(sc[SC_S1 + lane]*acc + sc[SC_T1 + lane], 0.0f);
    ft[((long)b*N_ + n)*64 + lane] = val;
    float v2 = val*val;
    #pragma unroll
    for (int s = 1; s < 64; s <<= 1) v2 += __shfl_xor(v2, s);
    if (lane == 0) sq[b*N_ + n] = v2;
}

// ---------------------------------------------------------------------------
// topk_sel2: k smallest (stable first-index ties) over RPL regs/lane,
// index = j*64+lane. Sortable-key + DPP value-min + ballot index recovery.
// ---------------------------------------------------------------------------
template<int RPL, int KSEL>
__device__ __forceinline__ void topk_sel2(float (&v)[RPL], int lane, int* __restrict__ out)
{
    unsigned key[RPL];
    #pragma unroll
    for (int j = 0; j < RPL; j++) key[j] = sortable_(v[j]);
    unsigned lk = key[0]; int ls = 0;
    #pragma unroll
    for (int j = 1; j < RPL; j++) { if (key[j] < lk) { lk = key[j]; ls = j; } }
    #pragma unroll 1
    for (int k = 0; k < KSEL; k++) {
        unsigned g = wave_minu(lk);
        unsigned long long cand = __ballot(lk == g);
        int gi;
        if (__popcll(cand) > 1) {
            // exact value tie across lanes: min global index (rare, exact)
            int ci = (lk == g) ? (ls*64 + lane) : 0x7FFFFFFF;
            #pragma unroll
            for (int s = 1; s < 64; s <<= 1) { int o = __shfl_xor(ci, s); ci = o < ci ? o : ci; }
            gi = ci;
        } else {
            int wl = __ffsll((long long)cand) - 1;
            gi = __shfl(ls, wl) * 64 + wl;
        }
        if (lane == 0) out[k] = gi;
        if (k + 1 < KSEL) {
            bool win = (lk == g) && (ls*64 + lane == gi);
            #pragma unroll
            for (int j = 0; j < RPL; j++) { if (win && j == ls) key[j] = 0xFFFFFFFFu; }
            lk = key[0]; ls = 0;
            #pragma unroll
            for (int j = 1; j < RPL; j++) { if (key[j] < lk) { lk = key[j]; ls = j; } }
        }
    }
}

// ---------------------------------------------------------------------------
// knn body, global-read refs (L1/L2-resident; no LDS, no barrier).
// Wave per query, 4 queries per 256-thread block.
// ---------------------------------------------------------------------------
template<int NREF, int RPL, int KSEL>
__device__ __forceinline__ void knn_gbody(
    const float* qp, long qBatch, int qsN, int qsD, int NQ,
    const float* rp, long rBatch, long rsN, long rsD,
    int* out, int bid)
{
    const int t = threadIdx.x, lane = t & 63, w = t >> 6;
    const int bpb = NQ / 4;
    const int b = bid / bpb;
    const int qi = (bid % bpb)*4 + w;
    const float* rb = rp + (long)b*rBatch;
    const float* qb = qp + (long)b*qBatch + (long)qi*qsN;
    float qx = qb[0], qy = qb[qsD], qz = qb[2*qsD];
    float sumq = __fadd_rn(__fadd_rn(__fmul_rn(qx,qx), __fmul_rn(qy,qy)), __fmul_rn(qz,qz));
    float v[RPL];
    #pragma unroll
    for (int j = 0; j < RPL; j++) {
        long n = j*64 + lane;
        float rx = rb[n*rsN];
        float ry = rb[n*rsN + rsD];
        float rz = rb[n*rsN + 2*rsD];
        float dot  = __fadd_rn(__fadd_rn(__fmul_rn(qx,rx), __fmul_rn(qy,ry)), __fmul_rn(qz,rz));
        float sumr = __fadd_rn(__fadd_rn(__fmul_rn(rx,rx), __fmul_rn(ry,ry)), __fmul_rn(rz,rz));
        v[j] = __fadd_rn(__fsub_rn(sumq, __fmul_rn(2.0f, dot)), sumr);
    }
    topk_sel2<RPL, KSEL>(v, lane, out + ((long)b*NQ + qi)*KSEL);
}

template<int NREF, int RPL, int KSEL>
__global__ void __launch_bounds__(256, 5) k_knn3d_g(
    const float* __restrict__ qp, long qBatch, int qsN, int qsD, int NQ,
    const float* __restrict__ rp, long rBatch, long rsN, long rsD,
    int* __restrict__ out)
{
    knn_gbody<NREF,RPL,KSEL>(qp, qBatch, qsN, qsD, NQ,
                             rp, rBatch, rsN, rsD, out, blockIdx.x);
}

// ---------------------------------------------------------------------------
// fused dispatch: blocks [0,16) run FPS1->FPS2 (4 waves, coords in registers,
// winner coords through merge table); blocks [16,16+8192) run geo-knn with
// global-read refs. LDS ~9.5KB total -> 5 blocks/CU (launch_bounds(256,5)).
// ---------------------------------------------------------------------------
__global__ void __launch_bounds__(256, 5) k_geoknn_fps(
    const float* __restrict__ x, int* __restrict__ idxg,
    int* __restrict__ fps1, float* __restrict__ nx1,
    int* __restrict__ fps2, float* __restrict__ nx2)
{
    __shared__ float  mx2[NP1], my2[NP1], mz2[NP1];   // 6 KiB (FPS1 -> FPS2)
    __shared__ int    sidx1[NP1];                     // 2 KiB
    __shared__ int    sidx2[NP2];                     // 1 KiB
    __shared__ float4 mrgc[2][4];                     // winner coords + value
    __shared__ int    mrgi[2][4];

    if (blockIdx.x < (unsigned)B_) {
        __builtin_amdgcn_s_setprio(3);
        const int t = threadIdx.x, lane = t & 63, wave = t >> 6;
        const int b = blockIdx.x;
        const float* pb = x + (long)b*6*N_;

        // register-resident coords: thread t owns points [8t, 8t+8)
        float px[8], py[8], pz[8], dl[8];
        {
            const float4* a4 = (const float4*)(pb + 8*t);
            const float4* b4 = (const float4*)(pb + N_ + 8*t);
            const float4* c4p = (const float4*)(pb + 2*N_ + 8*t);
            float4 a0 = a4[0], a1 = a4[1];
            float4 b0 = b4[0], b1 = b4[1];
            float4 c0 = c4p[0], c1 = c4p[1];
            px[0]=a0.x; px[1]=a0.y; px[2]=a0.z; px[3]=a0.w;
            px[4]=a1.x; px[5]=a1.y; px[6]=a1.z; px[7]=a1.w;
            py[0]=b0.x; py[1]=b0.y; py[2]=b0.z; py[3]=b0.w;
            py[4]=b1.x; py[5]=b1.y; py[6]=b1.z; py[7]=b1.w;
            pz[0]=c0.x; pz[1]=c0.y; pz[2]=c0.z; pz[3]=c0.w;
            pz[4]=c1.x; pz[5]=c1.y; pz[6]=c1.z; pz[7]=c1.w;
        }
        #pragma unroll
        for (int p = 0; p < 8; p++) dl[p] = 1e10f;

        // initial centroid = point 0 (uniform broadcast reads, once)
        float cx = pb[0], cy = pb[N_], cz = pb[2*N_];
        int far = 0;

        // ---------------- FPS1: 2048 -> 512 ----------------
        for (int i = 0; i < NP1; i++) {
            if (t == 0) { sidx1[i] = far; mx2[i] = cx; my2[i] = cy; mz2[i] = cz; }
            float bv = -1.0f; int bp = 0;
            #pragma unroll
            for (int p = 0; p < 8; p++) {
                float dx = __fsub_rn(px[p], cx);
                float dy = __fsub_rn(py[p], cy);
                float dz = __fsub_rn(pz[p], cz);
                float d  = __fadd_rn(__fadd_rn(__fmul_rn(dx,dx), __fmul_rn(dy,dy)), __fmul_rn(dz,dz));
                float nd = fminf(dl[p], d);
                dl[p] = nd;
                if (nd > bv) { bv = nd; bp = p; }   // ascending p: first-index ties
            }
            float gm = wave_max64(bv);
            unsigned long long cand = __ballot(bv == gm);
            int wl = __ffsll(cand) - 1;            // lowest lane = lowest orig idx
            // select candidate coords from own regs (static cndmask chain)
            float wx = px[0], wy = py[0], wz = pz[0];
            #pragma unroll
            for (int p = 1; p < 8; p++) {
                bool c = (bp == p);
                wx = c ? px[p] : wx; wy = c ? py[p] : wy; wz = c ? pz[p] : wz;
            }
            int par = i & 1;
            if (lane == wl) {
                mrgc[par][wave] = make_float4(wx, wy, wz, gm);
                mrgi[par][wave] = (((wave << 6) | wl) << 3) + bp;
            }
            __syncthreads();
            float4 e0 = mrgc[par][0];
            float fv = e0.w; int fi = mrgi[par][0];
            float ncx = e0.x, ncy = e0.y, ncz = e0.z;
            #pragma unroll
            for (int w2 = 1; w2 < 4; w2++) {
                float4 e2 = mrgc[par][w2]; int i2 = mrgi[par][w2];
                if (e2.w > fv) { fv = e2.w; fi = i2; ncx = e2.x; ncy = e2.y; ncz = e2.z; }
            }
            far = fi; cx = ncx; cy = ncy; cz = ncz;
        }
        __syncthreads();   // mir/sidx1 complete

        // write FPS1 outputs now (stores drain under FPS2's first barrier)
        int*   f1o = fps1 + b*NP1;
        float* n1o = nx1 + (long)b*NP1*3;
        for (int s = t; s < NP1; s += 256) {
            f1o[s] = sidx1[s];
            n1o[(long)s*3+0] = mx2[s];
            n1o[(long)s*3+1] = my2[s];
            n1o[(long)s*3+2] = mz2[s];
        }

        // ---------------- FPS2: 512 -> 256 (2 pts/thread from mir) ----------
        {
            const int n0 = t << 1;
            float ax = mx2[n0],   ay = my2[n0],   az = mz2[n0];
            float bx = mx2[n0+1], by = my2[n0+1], bz = mz2[n0+1];
            float dl0 = 1e10f, dl1 = 1e10f;
            int far2 = 0;
            float c2x = mx2[0], c2y = my2[0], c2z = mz2[0];
            for (int i = 0; i < NP2; i++) {
                if (t == 0) sidx2[i] = far2;
                float dx = __fsub_rn(ax, c2x), dy = __fsub_rn(ay, c2y), dz = __fsub_rn(az, c2z);
                float d0 = __fadd_rn(__fadd_rn(__fmul_rn(dx,dx), __fmul_rn(dy,dy)), __fmul_rn(dz,dz));
                dx = __fsub_rn(bx, c2x); dy = __fsub_rn(by, c2y); dz = __fsub_rn(bz, c2z);
                float d1 = __fadd_rn(__fadd_rn(__fmul_rn(dx,dx), __fmul_rn(dy,dy)), __fmul_rn(dz,dz));
                dl0 = fminf(dl0, d0);
                dl1 = fminf(dl1, d1);
                float bv = dl0; int bp = 0;
                if (dl1 > bv) { bv = dl1; bp = 1; }
                float gm = wave_max64(bv);
                unsigned long long cand = __ballot(bv == gm);
                int wl = __ffsll(cand) - 1;
                float wx = bp ? bx : ax, wy = bp ? by : ay, wz = bp ? bz : az;
                int par = i & 1;
                if (lane == wl) {
                    mrgc[par][wave] = make_float4(wx, wy, wz, gm);
                    mrgi[par][wave] = (((wave << 6) | wl) << 1) + bp;
                }
                __syncthreads();
                float4 e0 = mrgc[par][0];
                float fv = e0.w; int fi = mrgi[par][0];
                float ncx = e0.x, ncy = e0.y, ncz = e0.z;
                #pragma unroll
                for (int w2 = 1; w2 < 4; w2++) {
                    float4 e2 = mrgc[par][w2]; int i2 = mrgi[par][w2];
                    if (e2.w > fv) { fv = e2.w; fi = i2; ncx = e2.x; ncy = e2.y; ncz = e2.z; }
                }
                far2 = fi; c2x = ncx; c2y = ncy; c2z = ncz;
            }
        }
        __syncthreads();   // sidx2 visible

        int*   f2o = fps2 + b*NP2;
        float* n2o = nx2 + (long)b*NP2*3;
        for (int s = t; s < NP2; s += 256) {
            int j = sidx2[s];
            f2o[s] = j;
            n2o[(long)s*3+0] = mx2[j];
            n2o[(long)s*3+1] = my2[j];
            n2o[(long)s*3+2] = mz2[j];
        }
        __builtin_amdgcn_s_setprio(0);
        return;
    }
    knn_gbody<N_,32,KG>(x, (long)6*N_, 1, N_, N_,
                        x, (long)6*N_, 1, N_, idxg, blockIdx.x - B_);
}

// ---------------------------------------------------------------------------
// top-20 selection from a precomputed distance-chunk row (feature knn)
// ---------------------------------------------------------------------------
__global__ void __launch_bounds__(256) k_selectD(const float* __restrict__ D, int qbase,
                                                 int* __restrict__ out)
{
    const int t = threadIdx.x, lane = t & 63, w = t >> 6;
    const int r = blockIdx.x*4 + w;
    const int b = r / CHQ, qi = r % CHQ;
    const float* row = D + ((long)b*CHQ + qi) * N_;
    float v[32];
    #pragma unroll
    for (int j = 0; j < 32; j++) v[j] = row[j*64 + lane];
    topk_sel2<32, KG>(v, lane, out + ((long)b*N_ + qbase + qi)*KG);
}

// ---------------------------------------------------------------------------
// generic 64x64-tile fp32 GEMM: C[b] = A[b] * Bw^T with epilogues.
// ---------------------------------------------------------------------------
__global__ void __launch_bounds__(256) k_gemm(
    const float* __restrict__ A, long aBatch, int aRow,
    const float* __restrict__ Bw, long bBatch, int K,
    float* __restrict__ C, long cBatch, int cRow, int cCol0,
    int act, const float* __restrict__ sv, const float* __restrict__ tv,
    const float* __restrict__ sqv, int sqBatch, int sqQBase,
    int epi)
{
    __shared__ float As[64][68];
    __shared__ float Bs[64][68];
    const int b  = blockIdx.z;
    const int ib = blockIdx.x * 64;
    const int jb = blockIdx.y * 64;
    const int t  = threadIdx.x;
    const int tx = t & 15, ty = t >> 4;
    const float* Ab = A + (long)b * aBatch;
    const float* Bb = Bw + (long)b * bBatch;
    float acc[4][4];
    #pragma unroll
    for (int i = 0; i < 4; i++)
        #pragma unroll
        for (int j = 0; j < 4; j++) acc[i][j] = 0.0f;

    for (int kb = 0; kb < K; kb += 64) {
        #pragma unroll
        for (int m = 0; m < 4; m++) {
            int li = t + m*256; int r = li >> 4; int c4 = li & 15;
            float4 av = *(const float4*)(Ab + (long)(ib + r)*aRow + kb + c4*4);
            As[c4*4+0][r] = av.x; As[c4*4+1][r] = av.y;
            As[c4*4+2][r] = av.z; As[c4*4+3][r] = av.w;
            float4 bv = *(const float4*)(Bb + (long)(jb + r)*K + kb + c4*4);
            Bs[c4*4+0][r] = bv.x; Bs[c4*4+1][r] = bv.y;
            Bs[c4*4+2][r] = bv.z; Bs[c4*4+3][r] = bv.w;
        }
        __syncthreads();
        #pragma unroll 4
        for (int k = 0; k < 64; k++) {
            float4 a  = *(const float4*)&As[k][ty*4];
            float4 b4 = *(const float4*)&Bs[k][tx*4];
            acc[0][0] += a.x*b4.x; acc[0][1] += a.x*b4.y; acc[0][2] += a.x*b4.z; acc[0][3] += a.x*b4.w;
            acc[1][0] += a.y*b4.x; acc[1][1] += a.y*b4.y; acc[1][2] += a.y*b4.z; acc[1][3] += a.y*b4.w;
            acc[2][0] += a.z*b4.x; acc[2][1] += a.z*b4.y; acc[2][2] += a.z*b4.z; acc[2][3] += a.z*b4.w;
            acc[3][0] += a.w*b4.x; acc[3][1] += a.w*b4.y; acc[3][2] += a.w*b4.z; acc[3][3] += a.w*b4.w;
        }
        __syncthreads();
    }

    const int i0 = ib + ty*4;
    const int j0 = jb + tx*4;
    if (epi == 1) {
        #pragma unroll
        for (int ii = 0; ii < 4; ii++) {
            float sqq = sqv[(long)b*sqBatch + sqQBase + i0 + ii];
            #pragma unroll
            for (int jj = 0; jj < 4; jj++) {
                int r = j0 + jj;
                float sqr = sqv[(long)b*sqBatch + r];
                C[(long)b*cBatch + (long)(i0+ii)*cRow + r] = (sqq - 2.0f*acc[ii][jj]) + sqr;
            }
        }
    } else if (epi == 2) {
        #pragma unroll
        for (int ii = 0; ii < 4; ii++)
            #pragma unroll
            for (int jj = 0; jj < 4; jj++) {
                int j = j0 + jj;
                float vv = lrelu_(sv[j]*acc[ii][jj] + tv[j]);
                C[(long)b*cBatch + (long)j*cRow + (i0+ii)] = vv;
            }
    } else {
        #pragma unroll
        for (int ii = 0; ii < 4; ii++)
            #pragma unroll
            for (int jj = 0; jj < 4; jj++) {
                int j = j0 + jj;
                float vv = acc[ii][jj];
                if (act == 1) vv = fmaxf(sv[j]*vv + tv[j], 0.0f);
                else if (act == 2) vv = lrelu_(sv[j]*vv + tv[j]);
                C[(long)b*cBatch + (long)(i0+ii)*cRow + cCol0 + j] = vv;
            }
    }
}

// ---------------------------------------------------------------------------
// edge gather-max (geo + feat) + fuse GEMM + bn/lrelu -> out_feat_t (B,N,64)
// ---------------------------------------------------------------------------
__global__ void __launch_bounds__(256) k_edgefuse(
    const float* __restrict__ P, const int* __restrict__ idxg, const int* __restrict__ idxf,
    const float* __restrict__ wft, const float* __restrict__ sc,
    float* __restrict__ outf)
{
    __shared__ float wt[128*64];
    __shared__ float fused[4][128];
    const int t = threadIdx.x, lane = t & 63, w = t >> 6;
    for (int i = t; i < 128*64; i += 256) wt[i] = wft[i];
    const int pid = blockIdx.x*4 + w;
    const int b = pid >> 11, n = pid & (N_-1);
    const float* Prow = P + ((long)b*N_ + n)*256;
    const int* ig  = idxg + ((long)b*N_ + n)*KG;
    const int* ifx = idxf + ((long)b*N_ + n)*KG;
    float gmax = -FLT_MAX, hmax = -FLT_MAX;
    for (int k = 0; k < KG; k++) {
        int idg = ig[k];
        gmax = fmaxf(gmax, P[((long)b*N_ + idg)*256 + lane]);
        int idf = ifx[k];
        hmax = fmaxf(hmax, P[((long)b*N_ + idf)*256 + 128 + lane]);
    }
    float glin = gmax - Prow[lane]       + Prow[64 + lane];
    float hlin = hmax - Prow[128 + lane] + Prow[192 + lane];
    float gv = lrelu_(sc[SC_SGEO + lane]*glin + sc[SC_TGEO + lane]);
    float hv = lrelu_(sc[SC_SFEAT + lane]*hlin + sc[SC_TFEAT + lane]);
    fused[w][lane]      = gv;
    fused[w][64 + lane] = hv;
    __syncthreads();
    float acc = 0.0f;
    #pragma unroll 8
    for (int c4 = 0; c4 < 32; c4++) {
        float4 f = *(const float4*)&fused[w][c4*4];
        acc += f.x * wt[(c4*4+0)*64 + lane];
        acc += f.y * wt[(c4*4+1)*64 + lane];
        acc += f.z * wt[(c4*4+2)*64 + lane];
        acc += f.w * wt[(c4*4+3)*64 + lane];
    }
    float ov = lrelu_(sc[SC_SFUSE + lane]*acc + sc[SC_TFUSE + lane]);
    outf[((long)b*N_ + n)*64 + lane] = ov;
}

// ---------------------------------------------------------------------------
// local_op gather-max: out[b,s,o] = relu(bn(max_k Q[idx[k]][o] + Qc[crow][CO+o]))
// ---------------------------------------------------------------------------
template<int QN, int ROWW, int CO, int MROWS, int SO>
__global__ void __launch_bounds__(256) k_gathermax(
    const float* __restrict__ Q, const int* __restrict__ knn, const int* __restrict__ fpsi,
    const float* __restrict__ sv, const float* __restrict__ tv,
    float* __restrict__ outp, int outRow)
{
    const int t = threadIdx.x, lane = t & 63, w = t >> 6;
    const int pid = blockIdx.x*4 + w;
    const int b = pid / SO, s = pid % SO;
    const int* ix = knn + ((long)b*SO + s)*NSAMP;
    float mx[QN];
    #pragma unroll
    for (int q = 0; q < QN; q++) mx[q] = -FLT_MAX;
    for (int k = 0; k < NSAMP; k++) {
        int id = ix[k];
        const float* r = Q + ((long)b*MROWS + id)*ROWW;
        #pragma unroll
        for (int q = 0; q < QN; q++) mx[q] = fmaxf(mx[q], r[lane + 64*q]);
    }
    int crow = fpsi[b*SO + s];
    const float* cr = Q + ((long)b*MROWS + crow)*ROWW + CO;
    #pragma unroll
    for (int q = 0; q < QN; q++) {
        int o = lane + 64*q;
        float lin = mx[q] + cr[o];
        float val = fmaxf(sv[o]*lin + tv[o], 0.0f);
        outp[((long)b*SO + s)*outRow + o] = val;
    }
}

// ---------------------------------------------------------------------------
extern "C" void kernel_launch(void* const* d_in, const int* in_sizes, int n_in,
                              void* d_out, int out_size, void* d_ws, size_t ws_size,
                              hipStream_t stream)
{
    const float* x      = (const float*)d_in[0];
    const float* w1     = (const float*)d_in[1];
    const float* bn1    = (const float*)d_in[2];
    const float* w2     = (const float*)d_in[3];
    const float* bn2    = (const float*)d_in[4];
    const float* geow   = (const float*)d_in[5];
    const float* geobn  = (const float*)d_in[6];
    const float* featw  = (const float*)d_in[7];
    const float* featbn = (const float*)d_in[8];
    const float* fusew  = (const float*)d_in[9];
    const float* fusebn = (const float*)d_in[10];
    const float* gl0w   = (const float*)d_in[11];
    const float* gl0bn  = (const float*)d_in[12];
    const float* gl1w   = (const float*)d_in[13];
    const float* gl1bn  = (const float*)d_in[14];
    const float* wf     = (const float*)d_in[15];
    const float* bnfp   = (const float*)d_in[16];

    float* ws  = (float*)d_ws;
    float* out = (float*)d_out;

    float* FT   = ws + OFF_FT;
    float* SQ   = ws + OFF_SQ;
    float* BIG  = ws + OFF_BIG;
    int*   IDXG = (int*)(ws + OFF_IDXG);
    int*   IDXF = (int*)(ws + OFF_IDXF);
    float* OUTF = ws + OFF_OUTF;
    int*   FPS1 = (int*)(ws + OFF_FPS1);
    float* NX1  = ws + OFF_NX1;
    int*   IDX1 = (int*)(ws + OFF_IDX1);
    float* F0T  = ws + OFF_F0T;
    int*   FPS2 = (int*)(ws + OFF_FPS2);
    float* NX2  = ws + OFF_NX2;
    int*   IDX2 = (int*)(ws + OFF_IDX2);
    float* Q1B  = ws + OFF_Q1;
    float* V    = ws + OFF_V;
    float* WPP  = ws + OFF_WPP;
    float* WPQ0 = ws + OFF_WPQ0;
    float* WPQ1 = ws + OFF_WPQ1;
    float* WFT  = ws + OFF_WFT;
    float* SC   = ws + OFF_SC;
    const float* nfp = nullptr;

    hipLaunchKernelGGL(k_prep, dim3(64), dim3(256), 0, stream,
        bn1, bn2, geow, geobn, featw, featbn, fusew, fusebn, gl0w, gl0bn, gl1w, gl1bn, bnfp, ws);

    hipLaunchKernelGGL(k_feat0, dim3(B_*N_/4), dim3(256), 0, stream, x, w1, SC, FT, SQ);

    // fused: FPS1->FPS2 chain (16 leading blocks) + geo knn (8192 blocks)
    hipLaunchKernelGGL(k_geoknn_fps, dim3(B_ + B_*(N_/4)), dim3(256), 0, stream,
        x, IDXG, FPS1, NX1, FPS2, NX2);

    // feature knn: distance chunks + selection
    for (int ci = 0; ci < N_/CHQ; ci++) {
        int qbase = ci*CHQ;
        hipLaunchKernelGGL(k_gemm, dim3(CHQ/64, N_/64, B_), dim3(256), 0, stream,
            FT + (long)qbase*64, (long)N_*64, 64,
            FT, (long)N_*64, 64,
            BIG, (long)CHQ*N_, N_, 0,
            0, nfp, nfp, SQ, N_, qbase, 1);
        hipLaunchKernelGGL(k_selectD, dim3(B_*CHQ/4), dim3(256), 0, stream, BIG, qbase, IDXF);
    }

    // P projection (B,N,256) into BIG
    hipLaunchKernelGGL(k_gemm, dim3(N_/64, 256/64, B_), dim3(256), 0, stream,
        FT, (long)N_*64, 64, WPP, (long)0, 64,
        BIG, (long)N_*256, 256, 0, 0, nfp, nfp, nfp, 0, 0, 0);

    hipLaunchKernelGGL(k_edgefuse, dim3(B_*N_/4), dim3(256), 0, stream,
        BIG, IDXG, IDXF, WFT, SC, OUTF);

    // grouping knn 1 (queries = NX1 from fused FPS), global-read refs
    hipLaunchKernelGGL((k_knn3d_g<2048,32,32>), dim3(B_*(NP1/4)), dim3(256), 0, stream,
        NX1, (long)NP1*3, 3, 1, NP1, x, (long)6*N_, (long)1, (long)N_, IDX1);

    // Q0 projection (B,N,256) into BIG (P is dead now)
    hipLaunchKernelGGL(k_gemm, dim3(N_/64, 256/64, B_), dim3(256), 0, stream,
        OUTF, (long)N_*64, 64, WPQ0, (long)0, 64,
        BIG, (long)N_*256, 256, 0, 0, nfp, nfp, nfp, 0, 0, 0);

    hipLaunchKernelGGL((k_gathermax<2,256,128,2048,512>), dim3(B_*NP1/4), dim3(256), 0, stream,
        BIG, IDX1, FPS1, SC + SC_SGL0, SC + SC_TGL0, F0T, 128);

    // grouping knn 2 (queries = NX2), global-read refs
    hipLaunchKernelGGL((k_knn3d_g<512,8,32>), dim3(B_*(NP2/4)), dim3(256), 0, stream,
        NX2, (long)NP2*3, 3, 1, NP2, NX1, (long)NP1*3, (long)3, (long)1, IDX2);

    // Q1 projection (B,512,512)
    hipLaunchKernelGGL(k_gemm, dim3(NP1/64, 512/64, B_), dim3(256), 0, stream,
        F0T, (long)NP1*128, 128, WPQ1, (long)0, 128,
        Q1B, (long)NP1*512, 512, 0, 0, nfp, nfp, nfp, 0, 0, 0);

    hipLaunchKernelGGL((k_gathermax<4,512,256,512,256>), dim3(B_*NP2/4), dim3(256), 0, stream,
        Q1B, IDX2, FPS2, SC + SC_SGL1, SC + SC_TGL1, V, 1280);

    // x_skip -> V[:, :, 256:1280]  (A = f_t rows at stride 8 points)
    hipLaunchKernelGGL(k_gemm, dim3(NP2/64, 1024/64, B_), dim3(256), 0, stream,
        FT, (long)N_*64, 512, w2, (long)0, 64,
        V, (long)NP2*1280, 1280, 256, 1, SC + SC_S2, SC + SC_T2, nfp, 0, 0, 0);

    // final (B,512,256) = lrelu(bnf(wf . V^T)), transposed store
    hipLaunchKernelGGL(k_gemm, dim3(NP2/64, 512/64, B_), dim3(256), 0, stream,
        V, (long)NP2*1280, 1280, wf, (long)0, 1280,
        out, (long)512*256, 256, 0, 2, SC + SC_SF, SC + SC_TF, nfp, 0, 0, 2);

    (void)in_sizes; (void)n_in; (void)out_size; (void)ws_size;
}

// Round 10
// 1165.803 us; speedup vs baseline: 1.0817x; 1.0817x over previous
//
#include <hip/hip_runtime.h>
#include <float.h>
#include <math.h>

// ---------------------------------------------------------------------------
// SSFE_Net pipeline on MI355X. B=16, N=2048.
// R7: DPP/ballot topk. R8: de-staged knn refs (L1-resident).
// R9: topk_sel3 — per-lane top-2 cache + consumed bitmask; full rescan only on
//     a lane's SECOND win (~3/query instead of 20). Per-selection cost
//     160 -> ~30 VALU. readlane (SALU) index recovery. launch_bounds(256,4).
// ---------------------------------------------------------------------------

static constexpr int B_   = 16;
static constexpr int N_   = 2048;
static constexpr int NP1  = 512;
static constexpr int NP2  = 256;
static constexpr int KG   = 20;
static constexpr int NSAMP= 32;
static constexpr int CHQ  = 256;   // query chunk for feature-knn distance matrix

// workspace offsets (in float elements)
static constexpr long OFF_FT   = 0;
static constexpr long OFF_SQ   = OFF_FT   + (long)B_*N_*64;
static constexpr long OFF_BIG  = OFF_SQ   + (long)B_*N_;          // D chunk / P / Q0 (aliased)
static constexpr long OFF_IDXG = OFF_BIG  + (long)B_*N_*256;
static constexpr long OFF_IDXF = OFF_IDXG + (long)B_*N_*KG;
static constexpr long OFF_OUTF = OFF_IDXF + (long)B_*N_*KG;
static constexpr long OFF_FPS1 = OFF_OUTF + (long)B_*N_*64;
static constexpr long OFF_NX1  = OFF_FPS1 + (long)B_*NP1;
static constexpr long OFF_IDX1 = OFF_NX1  + (long)B_*NP1*3;
static constexpr long OFF_F0T  = OFF_IDX1 + (long)B_*NP1*NSAMP;
static constexpr long OFF_FPS2 = OFF_F0T  + (long)B_*NP1*128;
static constexpr long OFF_NX2  = OFF_FPS2 + (long)B_*NP2;
static constexpr long OFF_IDX2 = OFF_NX2  + (long)B_*NP2*3;
static constexpr long OFF_Q1   = OFF_IDX2 + (long)B_*NP2*NSAMP;
static constexpr long OFF_V    = OFF_Q1   + (long)B_*NP1*512;
static constexpr long OFF_WPP  = OFF_V    + (long)B_*NP2*1280;
static constexpr long OFF_WPQ0 = OFF_WPP  + 256*64;
static constexpr long OFF_WPQ1 = OFF_WPQ0 + 256*64;
static constexpr long OFF_WFT  = OFF_WPQ1 + 512*128;
static constexpr long OFF_SC   = OFF_WFT  + 128*64;

// SC (bn scale/shift) sub-offsets
static constexpr int SC_S1=0, SC_T1=64, SC_SGEO=128, SC_TGEO=192, SC_SFEAT=256, SC_TFEAT=320,
   SC_SFUSE=384, SC_TFUSE=448, SC_SGL0=512, SC_TGL0=640, SC_SGL1=768, SC_TGL1=1024,
   SC_S2=1280, SC_T2=2304, SC_SF=3328, SC_TF=3840;

__device__ __forceinline__ float lrelu_(float x) { return x >= 0.0f ? x : 0.2f * x; }

// DPP-accelerated wave64 max (value only; all lanes end with the max).
template<int CTRL>
__device__ __forceinline__ float dpp_max(float v) {
    int o = __builtin_amdgcn_update_dpp(0, __float_as_int(v), CTRL, 0xF, 0xF, true);
    return fmaxf(v, __int_as_float(o));
}
__device__ __forceinline__ float wave_max64(float v) {
    v = dpp_max<0xB1>(v);    // quad_perm(1,0,3,2)
    v = dpp_max<0x4E>(v);    // quad_perm(2,3,0,1)
    v = dpp_max<0x141>(v);   // row_half_mirror
    v = dpp_max<0x140>(v);   // row_mirror
    v = fmaxf(v, __shfl_xor(v, 16));
    v = fmaxf(v, __shfl_xor(v, 32));
    return v;
}

// DPP-accelerated wave64 unsigned min (value only).
template<int CTRL>
__device__ __forceinline__ unsigned dpp_minu(unsigned x) {
    unsigned o = (unsigned)__builtin_amdgcn_update_dpp(0, (int)x, CTRL, 0xF, 0xF, true);
    return o < x ? o : x;
}
__device__ __forceinline__ unsigned wave_minu(unsigned x) {
    x = dpp_minu<0xB1>(x);
    x = dpp_minu<0x4E>(x);
    x = dpp_minu<0x141>(x);
    x = dpp_minu<0x140>(x);
    { unsigned o = (unsigned)__shfl_xor((int)x, 16); x = o < x ? o : x; }
    { unsigned o = (unsigned)__shfl_xor((int)x, 32); x = o < x ? o : x; }
    return x;
}

// monotone float -> sortable u32 (handles negative values from rounding)
__device__ __forceinline__ unsigned sortable_(float f) {
    unsigned u = __float_as_uint(f);
    return u ^ ((unsigned)((int)u >> 31) | 0x80000000u);
}

// ---------------------------------------------------------------------------
// prep: bn scale/shift + packed weight matrices
// ---------------------------------------------------------------------------
__global__ void k_prep(const float* __restrict__ bn1, const float* __restrict__ bn2,
                       const float* __restrict__ geow, const float* __restrict__ geobn,
                       const float* __restrict__ featw, const float* __restrict__ featbn,
                       const float* __restrict__ fusew, const float* __restrict__ fusebn,
                       const float* __restrict__ gl0w, const float* __restrict__ gl0bn,
                       const float* __restrict__ gl1w, const float* __restrict__ gl1bn,
                       const float* __restrict__ bnfp, float* __restrict__ ws)
{
    const int tid = blockIdx.x * blockDim.x + threadIdx.x;
    const int nt  = gridDim.x * blockDim.x;
    float* sc = ws + OFF_SC;

    {
        const float* ps[8]  = {bn1, geobn, featbn, fusebn, gl0bn, gl1bn, bn2, bnfp};
        const int    ch[8]  = {64, 64, 64, 64, 128, 256, 1024, 512};
        const int    so[8]  = {SC_S1, SC_SGEO, SC_SFEAT, SC_SFUSE, SC_SGL0, SC_SGL1, SC_S2, SC_SF};
        const int    to[8]  = {SC_T1, SC_TGEO, SC_TFEAT, SC_TFUSE, SC_TGL0, SC_TGL1, SC_T2, SC_TF};
        for (int g = 0; g < 8; g++) {
            const float* p = ps[g]; int C = ch[g];
            for (int i = tid; i < C; i += nt) {
                float gg = p[i], bb = p[C+i], mm = p[2*C+i], vv = p[3*C+i];
                float s = gg * (1.0f / sqrtf(vv + 1e-5f));
                sc[so[g] + i] = s;
                sc[to[g] + i] = bb - mm * s;
            }
        }
    }
    for (int j = tid; j < 256*64; j += nt) {
        int o = j >> 6, c = j & 63; float v;
        if      (o < 64)  v = geow[o*128 + c];
        else if (o < 128) v = geow[(o-64)*128 + 64 + c];
        else if (o < 192) v = featw[(o-128)*128 + c];
        else              v = featw[(o-192)*128 + 64 + c];
        ws[OFF_WPP + j] = v;
    }
    for (int j = tid; j < 256*64; j += nt) {
        int o = j >> 6, c = j & 63; float v;
        if (o < 128) v = gl0w[o*128 + c];
        else         v = gl0w[(o-128)*128 + 64 + c] - gl0w[(o-128)*128 + c];
        ws[OFF_WPQ0 + j] = v;
    }
    for (int j = tid; j < 512*128; j += nt) {
        int o = j >> 7, c = j & 127; float v;
        if (o < 256) v = gl1w[o*256 + c];
        else         v = gl1w[(o-256)*256 + 128 + c] - gl1w[(o-256)*256 + c];
        ws[OFF_WPQ1 + j] = v;
    }
    for (int j = tid; j < 128*64; j += nt) {
        int c = j >> 6, o = j & 63;
        ws[OFF_WFT + j] = fusew[o*128 + c];
    }
}

// ---------------------------------------------------------------------------
// f_t[b][n][o] = relu(bn1(sum_c w1[o][c]*x[b][c][n])) ; sq[b][n] = sum_o f^2
// ---------------------------------------------------------------------------
__global__ void __launch_bounds__(256) k_feat0(const float* __restrict__ x,
                                               const float* __restrict__ w1,
                                               const float* __restrict__ sc,
                                               float* __restrict__ ft, float* __restrict__ sq)
{
    const int t = threadIdx.x, lane = t & 63, w = t >> 6;
    const int pid = blockIdx.x*4 + w;
    const int b = pid >> 11, n = pid & (N_-1);
    const float* xb = x + (long)b*6*N_ + n;
    float acc = 0.0f;
    #pragma unroll
    for (int c = 0; c < 6; c++) acc += w1[lane*6 + c] * xb[(long)c*N_];
    float val = fmaxf(sc[SC_S1 + lane]*acc + sc[SC_T1 + lane], 0.0f);
    ft[((long)b*N_ + n)*64 + lane] = val;
    float v2 = val*val;
    #pragma unroll
    for (int s = 1; s < 64; s <<= 1) v2 += __shfl_xor(v2, s);
    if (lane == 0) sq[b*N_ + n] = v2;
}

// ---------------------------------------------------------------------------
// topk_sel3: k smallest (stable first-index ties), index = j*64+lane.
// Per-lane top-2 cache (m1,s1,m2,s2) + consumed bitmask; a full rescan of the
// 32 keys happens only when a lane wins a SECOND time with an empty cache
// (~K^2/128 times per query instead of K). Reduce = DPP value-min; winner
// index recovered via ballot + SALU readlane.
// ---------------------------------------------------------------------------
template<int RPL, int KSEL>
__device__ __forceinline__ void topk_sel3(float (&v)[RPL], int lane, int* __restrict__ out)
{
    unsigned key[RPL];
    #pragma unroll
    for (int j = 0; j < RPL; j++) key[j] = sortable_(v[j]);

    unsigned consumed = 0;
    unsigned m1 = key[0]; int s1 = 0;
    unsigned m2 = 0xFFFFFFFFu; int s2 = 0;
    #pragma unroll
    for (int j = 1; j < RPL; j++) {
        unsigned kk = key[j];
        bool lt1 = kk < m1;
        bool lt2 = kk < m2;
        unsigned nm2 = lt1 ? m1 : (lt2 ? kk : m2);
        int      ns2 = lt1 ? s1 : (lt2 ? j  : s2);
        m1 = lt1 ? kk : m1;
        s1 = lt1 ? j  : s1;
        m2 = nm2; s2 = ns2;
    }

    #pragma unroll 1
    for (int k = 0; k < KSEL; k++) {
        unsigned g = wave_minu(m1);
        unsigned long long cand = __ballot(m1 == g);
        int gi;
        if (__popcll(cand) > 1) {
            // exact value tie across lanes: min global index (rare, exact)
            int ci = (m1 == g) ? (s1*64 + lane) : 0x7FFFFFFF;
            #pragma unroll
            for (int s = 1; s < 64; s <<= 1) { int o = __shfl_xor(ci, s); ci = o < ci ? o : ci; }
            gi = ci;
        } else {
            int wl = __ffsll((long long)cand) - 1;
            gi = __builtin_amdgcn_readlane(s1, wl) * 64 + wl;
        }
        if (lane == 0) out[k] = gi;
        if (k + 1 < KSEL) {
            bool win = (m1 == g) && (s1*64 + lane == gi);
            if (win) {
                consumed |= 1u << s1;
                m1 = m2; s1 = s2;
                m2 = 0xFFFFFFFFu;
            }
            bool need = win && (m1 == 0xFFFFFFFFu);
            if (__any(need)) {
                if (need) {
                    m1 = 0xFFFFFFFFu; s1 = 0; m2 = 0xFFFFFFFFu; s2 = 0;
                    #pragma unroll
                    for (int j = 0; j < RPL; j++) {
                        unsigned kk = ((consumed >> j) & 1u) ? 0xFFFFFFFFu : key[j];
                        bool lt1 = kk < m1;
                        bool lt2 = kk < m2;
                        unsigned nm2 = lt1 ? m1 : (lt2 ? kk : m2);
                        int      ns2 = lt1 ? s1 : (lt2 ? j  : s2);
                        m1 = lt1 ? kk : m1;
                        s1 = lt1 ? j  : s1;
                        m2 = nm2; s2 = ns2;
                    }
                }
            }
        }
    }
}

// ---------------------------------------------------------------------------
// knn body, global-read refs (L1/L2-resident; no LDS, no barrier).
// Wave per query, 4 queries per 256-thread block.
// ---------------------------------------------------------------------------
template<int NREF, int RPL, int KSEL>
__device__ __forceinline__ void knn_gbody(
    const float* qp, long qBatch, int qsN, int qsD, int NQ,
    const float* rp, long rBatch, long rsN, long rsD,
    int* out, int bid)
{
    const int t = threadIdx.x, lane = t & 63, w = t >> 6;
    const int bpb = NQ / 4;
    const int b = bid / bpb;
    const int qi = (bid % bpb)*4 + w;
    const float* rb = rp + (long)b*rBatch;
    const float* qb = qp + (long)b*qBatch + (long)qi*qsN;
    float qx = qb[0], qy = qb[qsD], qz = qb[2*qsD];
    float sumq = __fadd_rn(__fadd_rn(__fmul_rn(qx,qx), __fmul_rn(qy,qy)), __fmul_rn(qz,qz));
    float v[RPL];
    #pragma unroll
    for (int j = 0; j < RPL; j++) {
        long n = j*64 + lane;
        float rx = rb[n*rsN];
        float ry = rb[n*rsN + rsD];
        float rz = rb[n*rsN + 2*rsD];
        float dot  = __fadd_rn(__fadd_rn(__fmul_rn(qx,rx), __fmul_rn(qy,ry)), __fmul_rn(qz,rz));
        float sumr = __fadd_rn(__fadd_rn(__fmul_rn(rx,rx), __fmul_rn(ry,ry)), __fmul_rn(rz,rz));
        v[j] = __fadd_rn(__fsub_rn(sumq, __fmul_rn(2.0f, dot)), sumr);
    }
    topk_sel3<RPL, KSEL>(v, lane, out + ((long)b*NQ + qi)*KSEL);
}

template<int NREF, int RPL, int KSEL>
__global__ void __launch_bounds__(256, 4) k_knn3d_g(
    const float* __restrict__ qp, long qBatch, int qsN, int qsD, int NQ,
    const float* __restrict__ rp, long rBatch, long rsN, long rsD,
    int* __restrict__ out)
{
    knn_gbody<NREF,RPL,KSEL>(qp, qBatch, qsN, qsD, NQ,
                             rp, rBatch, rsN, rsD, out, blockIdx.x);
}

// ---------------------------------------------------------------------------
// fused dispatch: blocks [0,16) run FPS1->FPS2 (4 waves, coords in registers,
// winner coords through merge table); blocks [16,16+8192) run geo-knn with
// global-read refs. LDS ~9.5KB total.
// ---------------------------------------------------------------------------
__global__ void __launch_bounds__(256, 4) k_geoknn_fps(
    const float* __restrict__ x, int* __restrict__ idxg,
    int* __restrict__ fps1, float* __restrict__ nx1,
    int* __restrict__ fps2, float* __restrict__ nx2)
{
    __shared__ float  mx2[NP1], my2[NP1], mz2[NP1];   // 6 KiB (FPS1 -> FPS2)
    __shared__ int    sidx1[NP1];                     // 2 KiB
    __shared__ int    sidx2[NP2];                     // 1 KiB
    __shared__ float4 mrgc[2][4];                     // winner coords + value
    __shared__ int    mrgi[2][4];

    if (blockIdx.x < (unsigned)B_) {
        __builtin_amdgcn_s_setprio(3);
        const int t = threadIdx.x, lane = t & 63, wave = t >> 6;
        const int b = blockIdx.x;
        const float* pb = x + (long)b*6*N_;

        // register-resident coords: thread t owns points [8t, 8t+8)
        float px[8], py[8], pz[8], dl[8];
        {
            const float4* a4 = (const float4*)(pb + 8*t);
            const float4* b4 = (const float4*)(pb + N_ + 8*t);
            const float4* c4p = (const float4*)(pb + 2*N_ + 8*t);
            float4 a0 = a4[0], a1 = a4[1];
            float4 b0 = b4[0], b1 = b4[1];
            float4 c0 = c4p[0], c1 = c4p[1];
            px[0]=a0.x; px[1]=a0.y; px[2]=a0.z; px[3]=a0.w;
            px[4]=a1.x; px[5]=a1.y; px[6]=a1.z; px[7]=a1.w;
            py[0]=b0.x; py[1]=b0.y; py[2]=b0.z; py[3]=b0.w;
            py[4]=b1.x; py[5]=b1.y; py[6]=b1.z; py[7]=b1.w;
            pz[0]=c0.x; pz[1]=c0.y; pz[2]=c0.z; pz[3]=c0.w;
            pz[4]=c1.x; pz[5]=c1.y; pz[6]=c1.z; pz[7]=c1.w;
        }
        #pragma unroll
        for (int p = 0; p < 8; p++) dl[p] = 1e10f;

        float cx = pb[0], cy = pb[N_], cz = pb[2*N_];
        int far = 0;

        // ---------------- FPS1: 2048 -> 512 ----------------
        for (int i = 0; i < NP1; i++) {
            if (t == 0) { sidx1[i] = far; mx2[i] = cx; my2[i] = cy; mz2[i] = cz; }
            float bv = -1.0f; int bp = 0;
            #pragma unroll
            for (int p = 0; p < 8; p++) {
                float dx = __fsub_rn(px[p], cx);
                float dy = __fsub_rn(py[p], cy);
                float dz = __fsub_rn(pz[p], cz);
                float d  = __fadd_rn(__fadd_rn(__fmul_rn(dx,dx), __fmul_rn(dy,dy)), __fmul_rn(dz,dz));
                float nd = fminf(dl[p], d);
                dl[p] = nd;
                if (nd > bv) { bv = nd; bp = p; }   // ascending p: first-index ties
            }
            float gm = wave_max64(bv);
            unsigned long long cand = __ballot(bv == gm);
            int wl = __ffsll(cand) - 1;            // lowest lane = lowest orig idx
            float wx = px[0], wy = py[0], wz = pz[0];
            #pragma unroll
            for (int p = 1; p < 8; p++) {
                bool c = (bp == p);
                wx = c ? px[p] : wx; wy = c ? py[p] : wy; wz = c ? pz[p] : wz;
            }
            int par = i & 1;
            if (lane == wl) {
                mrgc[par][wave] = make_float4(wx, wy, wz, gm);
                mrgi[par][wave] = (((wave << 6) | wl) << 3) + bp;
            }
            __syncthreads();
            float4 e0 = mrgc[par][0];
            float fv = e0.w; int fi = mrgi[par][0];
            float ncx = e0.x, ncy = e0.y, ncz = e0.z;
            #pragma unroll
            for (int w2 = 1; w2 < 4; w2++) {
                float4 e2 = mrgc[par][w2]; int i2 = mrgi[par][w2];
                if (e2.w > fv) { fv = e2.w; fi = i2; ncx = e2.x; ncy = e2.y; ncz = e2.z; }
            }
            far = fi; cx = ncx; cy = ncy; cz = ncz;
        }
        __syncthreads();   // mir/sidx1 complete

        int*   f1o = fps1 + b*NP1;
        float* n1o = nx1 + (long)b*NP1*3;
        for (int s = t; s < NP1; s += 256) {
            f1o[s] = sidx1[s];
            n1o[(long)s*3+0] = mx2[s];
            n1o[(long)s*3+1] = my2[s];
            n1o[(long)s*3+2] = mz2[s];
        }

        // ---------------- FPS2: 512 -> 256 (2 pts/thread from mir) ----------
        {
            const int n0 = t << 1;
            float ax = mx2[n0],   ay = my2[n0],   az = mz2[n0];
            float bx = mx2[n0+1], by = my2[n0+1], bz = mz2[n0+1];
            float dl0 = 1e10f, dl1 = 1e10f;
            int far2 = 0;
            float c2x = mx2[0], c2y = my2[0], c2z = mz2[0];
            for (int i = 0; i < NP2; i++) {
                if (t == 0) sidx2[i] = far2;
                float dx = __fsub_rn(ax, c2x), dy = __fsub_rn(ay, c2y), dz = __fsub_rn(az, c2z);
                float d0 = __fadd_rn(__fadd_rn(__fmul_rn(dx,dx), __fmul_rn(dy,dy)), __fmul_rn(dz,dz));
                dx = __fsub_rn(bx, c2x); dy = __fsub_rn(by, c2y); dz = __fsub_rn(bz, c2z);
                float d1 = __fadd_rn(__fadd_rn(__fmul_rn(dx,dx), __fmul_rn(dy,dy)), __fmul_rn(dz,dz));
                dl0 = fminf(dl0, d0);
                dl1 = fminf(dl1, d1);
                float bv = dl0; int bp = 0;
                if (dl1 > bv) { bv = dl1; bp = 1; }
                float gm = wave_max64(bv);
                unsigned long long cand = __ballot(bv == gm);
                int wl = __ffsll(cand) - 1;
                float wx = bp ? bx : ax, wy = bp ? by : ay, wz = bp ? bz : az;
                int par = i & 1;
                if (lane == wl) {
                    mrgc[par][wave] = make_float4(wx, wy, wz, gm);
                    mrgi[par][wave] = (((wave << 6) | wl) << 1) + bp;
                }
                __syncthreads();
                float4 e0 = mrgc[par][0];
                float fv = e0.w; int fi = mrgi[par][0];
                float ncx = e0.x, ncy = e0.y, ncz = e0.z;
                #pragma unroll
                for (int w2 = 1; w2 < 4; w2++) {
                    float4 e2 = mrgc[par][w2]; int i2 = mrgi[par][w2];
                    if (e2.w > fv) { fv = e2.w; fi = i2; ncx = e2.x; ncy = e2.y; ncz = e2.z; }
                }
                far2 = fi; c2x = ncx; c2y = ncy; c2z = ncz;
            }
        }
        __syncthreads();   // sidx2 visible

        int*   f2o = fps2 + b*NP2;
        float* n2o = nx2 + (long)b*NP2*3;
        for (int s = t; s < NP2; s += 256) {
            int j = sidx2[s];
            f2o[s] = j;
            n2o[(long)s*3+0] = mx2[j];
            n2o[(long)s*3+1] = my2[j];
            n2o[(long)s*3+2] = mz2[j];
        }
        __builtin_amdgcn_s_setprio(0);
        return;
    }
    knn_gbody<N_,32,KG>(x, (long)6*N_, 1, N_, N_,
                        x, (long)6*N_, 1, N_, idxg, blockIdx.x - B_);
}

// ---------------------------------------------------------------------------
// top-20 selection from a precomputed distance-chunk row (feature knn)
// ---------------------------------------------------------------------------
__global__ void __launch_bounds__(256, 4) k_selectD(const float* __restrict__ D, int qbase,
                                                    int* __restrict__ out)
{
    const int t = threadIdx.x, lane = t & 63, w = t >> 6;
    const int r = blockIdx.x*4 + w;
    const int b = r / CHQ, qi = r % CHQ;
    const float* row = D + ((long)b*CHQ + qi) * N_;
    float v[32];
    #pragma unroll
    for (int j = 0; j < 32; j++) v[j] = row[j*64 + lane];
    topk_sel3<32, KG>(v, lane, out + ((long)b*N_ + qbase + qi)*KG);
}

// ---------------------------------------------------------------------------
// generic 64x64-tile fp32 GEMM: C[b] = A[b] * Bw^T with epilogues.
// ---------------------------------------------------------------------------
__global__ void __launch_bounds__(256) k_gemm(
    const float* __restrict__ A, long aBatch, int aRow,
    const float* __restrict__ Bw, long bBatch, int K,
    float* __restrict__ C, long cBatch, int cRow, int cCol0,
    int act, const float* __restrict__ sv, const float* __restrict__ tv,
    const float* __restrict__ sqv, int sqBatch, int sqQBase,
    int epi)
{
    __shared__ float As[64][68];
    __shared__ float Bs[64][68];
    const int b  = blockIdx.z;
    const int ib = blockIdx.x * 64;
    const int jb = blockIdx.y * 64;
    const int t  = threadIdx.x;
    const int tx = t & 15, ty = t >> 4;
    const float* Ab = A + (long)b * aBatch;
    const float* Bb = Bw + (long)b * bBatch;
    float acc[4][4];
    #pragma unroll
    for (int i = 0; i < 4; i++)
        #pragma unroll
        for (int j = 0; j < 4; j++) acc[i][j] = 0.0f;

    for (int kb = 0; kb < K; kb += 64) {
        #pragma unroll
        for (int m = 0; m < 4; m++) {
            int li = t + m*256; int r = li >> 4; int c4 = li & 15;
            float4 av = *(const float4*)(Ab + (long)(ib + r)*aRow + kb + c4*4);
            As[c4*4+0][r] = av.x; As[c4*4+1][r] = av.y;
            As[c4*4+2][r] = av.z; As[c4*4+3][r] = av.w;
            float4 bv = *(const float4*)(Bb + (long)(jb + r)*K + kb + c4*4);
            Bs[c4*4+0][r] = bv.x; Bs[c4*4+1][r] = bv.y;
            Bs[c4*4+2][r] = bv.z; Bs[c4*4+3][r] = bv.w;
        }
        __syncthreads();
        #pragma unroll 4
        for (int k = 0; k < 64; k++) {
            float4 a  = *(const float4*)&As[k][ty*4];
            float4 b4 = *(const float4*)&Bs[k][tx*4];
            acc[0][0] += a.x*b4.x; acc[0][1] += a.x*b4.y; acc[0][2] += a.x*b4.z; acc[0][3] += a.x*b4.w;
            acc[1][0] += a.y*b4.x; acc[1][1] += a.y*b4.y; acc[1][2] += a.y*b4.z; acc[1][3] += a.y*b4.w;
            acc[2][0] += a.z*b4.x; acc[2][1] += a.z*b4.y; acc[2][2] += a.z*b4.z; acc[2][3] += a.z*b4.w;
            acc[3][0] += a.w*b4.x; acc[3][1] += a.w*b4.y; acc[3][2] += a.w*b4.z; acc[3][3] += a.w*b4.w;
        }
        __syncthreads();
    }

    const int i0 = ib + ty*4;
    const int j0 = jb + tx*4;
    if (epi == 1) {
        #pragma unroll
        for (int ii = 0; ii < 4; ii++) {
            float sqq = sqv[(long)b*sqBatch + sqQBase + i0 + ii];
            #pragma unroll
            for (int jj = 0; jj < 4; jj++) {
                int r = j0 + jj;
                float sqr = sqv[(long)b*sqBatch + r];
                C[(long)b*cBatch + (long)(i0+ii)*cRow + r] = (sqq - 2.0f*acc[ii][jj]) + sqr;
            }
        }
    } else if (epi == 2) {
        #pragma unroll
        for (int ii = 0; ii < 4; ii++)
            #pragma unroll
            for (int jj = 0; jj < 4; jj++) {
                int j = j0 + jj;
                float vv = lrelu_(sv[j]*acc[ii][jj] + tv[j]);
                C[(long)b*cBatch + (long)j*cRow + (i0+ii)] = vv;
            }
    } else {
        #pragma unroll
        for (int ii = 0; ii < 4; ii++)
            #pragma unroll
            for (int jj = 0; jj < 4; jj++) {
                int j = j0 + jj;
                float vv = acc[ii][jj];
                if (act == 1) vv = fmaxf(sv[j]*vv + tv[j], 0.0f);
                else if (act == 2) vv = lrelu_(sv[j]*vv + tv[j]);
                C[(long)b*cBatch + (long)(i0+ii)*cRow + cCol0 + j] = vv;
            }
    }
}

// ---------------------------------------------------------------------------
// edge gather-max (geo + feat) + fuse GEMM + bn/lrelu -> out_feat_t (B,N,64)
// ---------------------------------------------------------------------------
__global__ void __launch_bounds__(256) k_edgefuse(
    const float* __restrict__ P, const int* __restrict__ idxg, const int* __restrict__ idxf,
    const float* __restrict__ wft, const float* __restrict__ sc,
    float* __restrict__ outf)
{
    __shared__ float wt[128*64];
    __shared__ float fused[4][128];
    const int t = threadIdx.x, lane = t & 63, w = t >> 6;
    for (int i = t; i < 128*64; i += 256) wt[i] = wft[i];
    const int pid = blockIdx.x*4 + w;
    const int b = pid >> 11, n = pid & (N_-1);
    const float* Prow = P + ((long)b*N_ + n)*256;
    const int* ig  = idxg + ((long)b*N_ + n)*KG;
    const int* ifx = idxf + ((long)b*N_ + n)*KG;
    float gmax = -FLT_MAX, hmax = -FLT_MAX;
    for (int k = 0; k < KG; k++) {
        int idg = ig[k];
        gmax = fmaxf(gmax, P[((long)b*N_ + idg)*256 + lane]);
        int idf = ifx[k];
        hmax = fmaxf(hmax, P[((long)b*N_ + idf)*256 + 128 + lane]);
    }
    float glin = gmax - Prow[lane]       + Prow[64 + lane];
    float hlin = hmax - Prow[128 + lane] + Prow[192 + lane];
    float gv = lrelu_(sc[SC_SGEO + lane]*glin + sc[SC_TGEO + lane]);
    float hv = lrelu_(sc[SC_SFEAT + lane]*hlin + sc[SC_TFEAT + lane]);
    fused[w][lane]      = gv;
    fused[w][64 + lane] = hv;
    __syncthreads();
    float acc = 0.0f;
    #pragma unroll 8
    for (int c4 = 0; c4 < 32; c4++) {
        float4 f = *(const float4*)&fused[w][c4*4];
        acc += f.x * wt[(c4*4+0)*64 + lane];
        acc += f.y * wt[(c4*4+1)*64 + lane];
        acc += f.z * wt[(c4*4+2)*64 + lane];
        acc += f.w * wt[(c4*4+3)*64 + lane];
    }
    float ov = lrelu_(sc[SC_SFUSE + lane]*acc + sc[SC_TFUSE + lane]);
    outf[((long)b*N_ + n)*64 + lane] = ov;
}

// ---------------------------------------------------------------------------
// local_op gather-max: out[b,s,o] = relu(bn(max_k Q[idx[k]][o] + Qc[crow][CO+o]))
// ---------------------------------------------------------------------------
template<int QN, int ROWW, int CO, int MROWS, int SO>
__global__ void __launch_bounds__(256) k_gathermax(
    const float* __restrict__ Q, const int* __restrict__ knn, const int* __restrict__ fpsi,
    const float* __restrict__ sv, const float* __restrict__ tv,
    float* __restrict__ outp, int outRow)
{
    const int t = threadIdx.x, lane = t & 63, w = t >> 6;
    const int pid = blockIdx.x*4 + w;
    const int b = pid / SO, s = pid % SO;
    const int* ix = knn + ((long)b*SO + s)*NSAMP;
    float mx[QN];
    #pragma unroll
    for (int q = 0; q < QN; q++) mx[q] = -FLT_MAX;
    for (int k = 0; k < NSAMP; k++) {
        int id = ix[k];
        const float* r = Q + ((long)b*MROWS + id)*ROWW;
        #pragma unroll
        for (int q = 0; q < QN; q++) mx[q] = fmaxf(mx[q], r[lane + 64*q]);
    }
    int crow = fpsi[b*SO + s];
    const float* cr = Q + ((long)b*MROWS + crow)*ROWW + CO;
    #pragma unroll
    for (int q = 0; q < QN; q++) {
        int o = lane + 64*q;
        float lin = mx[q] + cr[o];
        float val = fmaxf(sv[o]*lin + tv[o], 0.0f);
        outp[((long)b*SO + s)*outRow + o] = val;
    }
}

// ---------------------------------------------------------------------------
extern "C" void kernel_launch(void* const* d_in, const int* in_sizes, int n_in,
                              void* d_out, int out_size, void* d_ws, size_t ws_size,
                              hipStream_t stream)
{
    const float* x      = (const float*)d_in[0];
    const float* w1     = (const float*)d_in[1];
    const float* bn1    = (const float*)d_in[2];
    const float* w2     = (const float*)d_in[3];
    const float* bn2    = (const float*)d_in[4];
    const float* geow   = (const float*)d_in[5];
    const float* geobn  = (const float*)d_in[6];
    const float* featw  = (const float*)d_in[7];
    const float* featbn = (const float*)d_in[8];
    const float* fusew  = (const float*)d_in[9];
    const float* fusebn = (const float*)d_in[10];
    const float* gl0w   = (const float*)d_in[11];
    const float* gl0bn  = (const float*)d_in[12];
    const float* gl1w   = (const float*)d_in[13];
    const float* gl1bn  = (const float*)d_in[14];
    const float* wf     = (const float*)d_in[15];
    const float* bnfp   = (const float*)d_in[16];

    float* ws  = (float*)d_ws;
    float* out = (float*)d_out;

    float* FT   = ws + OFF_FT;
    float* SQ   = ws + OFF_SQ;
    float* BIG  = ws + OFF_BIG;
    int*   IDXG = (int*)(ws + OFF_IDXG);
    int*   IDXF = (int*)(ws + OFF_IDXF);
    float* OUTF = ws + OFF_OUTF;
    int*   FPS1 = (int*)(ws + OFF_FPS1);
    float* NX1  = ws + OFF_NX1;
    int*   IDX1 = (int*)(ws + OFF_IDX1);
    float* F0T  = ws + OFF_F0T;
    int*   FPS2 = (int*)(ws + OFF_FPS2);
    float* NX2  = ws + OFF_NX2;
    int*   IDX2 = (int*)(ws + OFF_IDX2);
    float* Q1B  = ws + OFF_Q1;
    float* V    = ws + OFF_V;
    float* WPP  = ws + OFF_WPP;
    float* WPQ0 = ws + OFF_WPQ0;
    float* WPQ1 = ws + OFF_WPQ1;
    float* WFT  = ws + OFF_WFT;
    float* SC   = ws + OFF_SC;
    const float* nfp = nullptr;

    hipLaunchKernelGGL(k_prep, dim3(64), dim3(256), 0, stream,
        bn1, bn2, geow, geobn, featw, featbn, fusew, fusebn, gl0w, gl0bn, gl1w, gl1bn, bnfp, ws);

    hipLaunchKernelGGL(k_feat0, dim3(B_*N_/4), dim3(256), 0, stream, x, w1, SC, FT, SQ);

    // fused: FPS1->FPS2 chain (16 leading blocks) + geo knn (8192 blocks)
    hipLaunchKernelGGL(k_geoknn_fps, dim3(B_ + B_*(N_/4)), dim3(256), 0, stream,
        x, IDXG, FPS1, NX1, FPS2, NX2);

    // feature knn: distance chunks + selection
    for (int ci = 0; ci < N_/CHQ; ci++) {
        int qbase = ci*CHQ;
        hipLaunchKernelGGL(k_gemm, dim3(CHQ/64, N_/64, B_), dim3(256), 0, stream,
            FT + (long)qbase*64, (long)N_*64, 64,
            FT, (long)N_*64, 64,
            BIG, (long)CHQ*N_, N_, 0,
            0, nfp, nfp, SQ, N_, qbase, 1);
        hipLaunchKernelGGL(k_selectD, dim3(B_*CHQ/4), dim3(256), 0, stream, BIG, qbase, IDXF);
    }

    // P projection (B,N,256) into BIG
    hipLaunchKernelGGL(k_gemm, dim3(N_/64, 256/64, B_), dim3(256), 0, stream,
        FT, (long)N_*64, 64, WPP, (long)0, 64,
        BIG, (long)N_*256, 256, 0, 0, nfp, nfp, nfp, 0, 0, 0);

    hipLaunchKernelGGL(k_edgefuse, dim3(B_*N_/4), dim3(256), 0, stream,
        BIG, IDXG, IDXF, WFT, SC, OUTF);

    // grouping knn 1 (queries = NX1 from fused FPS), global-read refs
    hipLaunchKernelGGL((k_knn3d_g<2048,32,32>), dim3(B_*(NP1/4)), dim3(256), 0, stream,
        NX1, (long)NP1*3, 3, 1, NP1, x, (long)6*N_, (long)1, (long)N_, IDX1);

    // Q0 projection (B,N,256) into BIG (P is dead now)
    hipLaunchKernelGGL(k_gemm, dim3(N_/64, 256/64, B_), dim3(256), 0, stream,
        OUTF, (long)N_*64, 64, WPQ0, (long)0, 64,
        BIG, (long)N_*256, 256, 0, 0, nfp, nfp, nfp, 0, 0, 0);

    hipLaunchKernelGGL((k_gathermax<2,256,128,2048,512>), dim3(B_*NP1/4), dim3(256), 0, stream,
        BIG, IDX1, FPS1, SC + SC_SGL0, SC + SC_TGL0, F0T, 128);

    // grouping knn 2 (queries = NX2), global-read refs
    hipLaunchKernelGGL((k_knn3d_g<512,8,32>), dim3(B_*(NP2/4)), dim3(256), 0, stream,
        NX2, (long)NP2*3, 3, 1, NP2, NX1, (long)NP1*3, (long)3, (long)1, IDX2);

    // Q1 projection (B,512,512)
    hipLaunchKernelGGL(k_gemm, dim3(NP1/64, 512/64, B_), dim3(256), 0, stream,
        F0T, (long)NP1*128, 128, WPQ1, (long)0, 128,
        Q1B, (long)NP1*512, 512, 0, 0, nfp, nfp, nfp, 0, 0, 0);

    hipLaunchKernelGGL((k_gathermax<4,512,256,512,256>), dim3(B_*NP2/4), dim3(256), 0, stream,
        Q1B, IDX2, FPS2, SC + SC_SGL1, SC + SC_TGL1, V, 1280);

    // x_skip -> V[:, :, 256:1280]  (A = f_t rows at stride 8 points)
    hipLaunchKernelGGL(k_gemm, dim3(NP2/64, 1024/64, B_), dim3(256), 0, stream,
        FT, (long)N_*64, 512, w2, (long)0, 64,
        V, (long)NP2*1280, 1280, 256, 1, SC + SC_S2, SC + SC_T2, nfp, 0, 0, 0);

    // final (B,512,256) = lrelu(bnf(wf . V^T)), transposed store
    hipLaunchKernelGGL(k_gemm, dim3(NP2/64, 512/64, B_), dim3(256), 0, stream,
        V, (long)NP2*1280, 1280, wf, (long)0, 1280,
        out, (long)512*256, 256, 0, 2, SC + SC_SF, SC + SC_TF, nfp, 0, 0, 2);

    (void)in_sizes; (void)n_in; (void)out_size; (void)ws_size;
}

// Round 11
// 1101.890 us; speedup vs baseline: 1.1445x; 1.0580x over previous
//
#include <hip/hip_runtime.h>
#include <float.h>
#include <math.h>

// ---------------------------------------------------------------------------
// SSFE_Net pipeline on MI355X. B=16, N=2048.
// R9: topk_sel3 (top-2 cache) — knn halved; FPS exposed as the 477us tail.
// R10: FPS wave-reduce rebuilt as pure-VALU DPP ladder (quad_perm x2,
//      row_half_mirror, row_mirror, row_bcast15, row_bcast31) + readlane
//      SGPR broadcast — removes the two ds_swizzle shuffles (~200cy serial)
//      from the per-iteration critical path. Winner coords/slot via readlane.
// ---------------------------------------------------------------------------

static constexpr int B_   = 16;
static constexpr int N_   = 2048;
static constexpr int NP1  = 512;
static constexpr int NP2  = 256;
static constexpr int KG   = 20;
static constexpr int NSAMP= 32;
static constexpr int CHQ  = 256;   // query chunk for feature-knn distance matrix

// workspace offsets (in float elements)
static constexpr long OFF_FT   = 0;
static constexpr long OFF_SQ   = OFF_FT   + (long)B_*N_*64;
static constexpr long OFF_BIG  = OFF_SQ   + (long)B_*N_;          // D chunk / P / Q0 (aliased)
static constexpr long OFF_IDXG = OFF_BIG  + (long)B_*N_*256;
static constexpr long OFF_IDXF = OFF_IDXG + (long)B_*N_*KG;
static constexpr long OFF_OUTF = OFF_IDXF + (long)B_*N_*KG;
static constexpr long OFF_FPS1 = OFF_OUTF + (long)B_*N_*64;
static constexpr long OFF_NX1  = OFF_FPS1 + (long)B_*NP1;
static constexpr long OFF_IDX1 = OFF_NX1  + (long)B_*NP1*3;
static constexpr long OFF_F0T  = OFF_IDX1 + (long)B_*NP1*NSAMP;
static constexpr long OFF_FPS2 = OFF_F0T  + (long)B_*NP1*128;
static constexpr long OFF_NX2  = OFF_FPS2 + (long)B_*NP2;
static constexpr long OFF_IDX2 = OFF_NX2  + (long)B_*NP2*3;
static constexpr long OFF_Q1   = OFF_IDX2 + (long)B_*NP2*NSAMP;
static constexpr long OFF_V    = OFF_Q1   + (long)B_*NP1*512;
static constexpr long OFF_WPP  = OFF_V    + (long)B_*NP2*1280;
static constexpr long OFF_WPQ0 = OFF_WPP  + 256*64;
static constexpr long OFF_WPQ1 = OFF_WPQ0 + 256*64;
static constexpr long OFF_WFT  = OFF_WPQ1 + 512*128;
static constexpr long OFF_SC   = OFF_WFT  + 128*64;

// SC (bn scale/shift) sub-offsets
static constexpr int SC_S1=0, SC_T1=64, SC_SGEO=128, SC_TGEO=192, SC_SFEAT=256, SC_TFEAT=320,
   SC_SFUSE=384, SC_TFUSE=448, SC_SGL0=512, SC_TGL0=640, SC_SGL1=768, SC_TGL1=1024,
   SC_S2=1280, SC_T2=2304, SC_SF=3328, SC_TF=3840;

__device__ __forceinline__ float lrelu_(float x) { return x >= 0.0f ? x : 0.2f * x; }

// masked DPP max step: masked-off rows keep v (old = v)
template<int CTRL, int RM>
__device__ __forceinline__ float dpp_maxm(float v) {
    int o = __builtin_amdgcn_update_dpp(__float_as_int(v), __float_as_int(v),
                                        CTRL, RM, 0xF, false);
    return fmaxf(v, __int_as_float(o));
}
// pure-VALU wave64 max -> uniform SGPR value (no ds_swizzle/bpermute).
__device__ __forceinline__ float wave_max64_sgpr(float v) {
    v = dpp_maxm<0xB1, 0xF>(v);   // quad_perm(1,0,3,2)
    v = dpp_maxm<0x4E, 0xF>(v);   // quad_perm(2,3,0,1)
    v = dpp_maxm<0x141,0xF>(v);   // row_half_mirror
    v = dpp_maxm<0x140,0xF>(v);   // row_mirror  -> row max in all 16 lanes
    v = dpp_maxm<0x142,0xA>(v);   // row_bcast15 -> rows 1,3 combine
    v = dpp_maxm<0x143,0xC>(v);   // row_bcast31 -> rows 2,3 combine; lane63 = max
    return __int_as_float(__builtin_amdgcn_readlane(__float_as_int(v), 63));
}

// DPP-accelerated wave64 unsigned min (value only, all lanes) — knn topk.
template<int CTRL>
__device__ __forceinline__ unsigned dpp_minu(unsigned x) {
    unsigned o = (unsigned)__builtin_amdgcn_update_dpp(0, (int)x, CTRL, 0xF, 0xF, true);
    return o < x ? o : x;
}
__device__ __forceinline__ unsigned wave_minu(unsigned x) {
    x = dpp_minu<0xB1>(x);
    x = dpp_minu<0x4E>(x);
    x = dpp_minu<0x141>(x);
    x = dpp_minu<0x140>(x);
    { unsigned o = (unsigned)__shfl_xor((int)x, 16); x = o < x ? o : x; }
    { unsigned o = (unsigned)__shfl_xor((int)x, 32); x = o < x ? o : x; }
    return x;
}

// monotone float -> sortable u32 (handles negative values from rounding)
__device__ __forceinline__ unsigned sortable_(float f) {
    unsigned u = __float_as_uint(f);
    return u ^ ((unsigned)((int)u >> 31) | 0x80000000u);
}

// ---------------------------------------------------------------------------
// prep: bn scale/shift + packed weight matrices
// ---------------------------------------------------------------------------
__global__ void k_prep(const float* __restrict__ bn1, const float* __restrict__ bn2,
                       const float* __restrict__ geow, const float* __restrict__ geobn,
                       const float* __restrict__ featw, const float* __restrict__ featbn,
                       const float* __restrict__ fusew, const float* __restrict__ fusebn,
                       const float* __restrict__ gl0w, const float* __restrict__ gl0bn,
                       const float* __restrict__ gl1w, const float* __restrict__ gl1bn,
                       const float* __restrict__ bnfp, float* __restrict__ ws)
{
    const int tid = blockIdx.x * blockDim.x + threadIdx.x;
    const int nt  = gridDim.x * blockDim.x;
    float* sc = ws + OFF_SC;

    {
        const float* ps[8]  = {bn1, geobn, featbn, fusebn, gl0bn, gl1bn, bn2, bnfp};
        const int    ch[8]  = {64, 64, 64, 64, 128, 256, 1024, 512};
        const int    so[8]  = {SC_S1, SC_SGEO, SC_SFEAT, SC_SFUSE, SC_SGL0, SC_SGL1, SC_S2, SC_SF};
        const int    to[8]  = {SC_T1, SC_TGEO, SC_TFEAT, SC_TFUSE, SC_TGL0, SC_TGL1, SC_T2, SC_TF};
        for (int g = 0; g < 8; g++) {
            const float* p = ps[g]; int C = ch[g];
            for (int i = tid; i < C; i += nt) {
                float gg = p[i], bb = p[C+i], mm = p[2*C+i], vv = p[3*C+i];
                float s = gg * (1.0f / sqrtf(vv + 1e-5f));
                sc[so[g] + i] = s;
                sc[to[g] + i] = bb - mm * s;
            }
        }
    }
    for (int j = tid; j < 256*64; j += nt) {
        int o = j >> 6, c = j & 63; float v;
        if      (o < 64)  v = geow[o*128 + c];
        else if (o < 128) v = geow[(o-64)*128 + 64 + c];
        else if (o < 192) v = featw[(o-128)*128 + c];
        else              v = featw[(o-192)*128 + 64 + c];
        ws[OFF_WPP + j] = v;
    }
    for (int j = tid; j < 256*64; j += nt) {
        int o = j >> 6, c = j & 63; float v;
        if (o < 128) v = gl0w[o*128 + c];
        else         v = gl0w[(o-128)*128 + 64 + c] - gl0w[(o-128)*128 + c];
        ws[OFF_WPQ0 + j] = v;
    }
    for (int j = tid; j < 512*128; j += nt) {
        int o = j >> 7, c = j & 127; float v;
        if (o < 256) v = gl1w[o*256 + c];
        else         v = gl1w[(o-256)*256 + 128 + c] - gl1w[(o-256)*256 + c];
        ws[OFF_WPQ1 + j] = v;
    }
    for (int j = tid; j < 128*64; j += nt) {
        int c = j >> 6, o = j & 63;
        ws[OFF_WFT + j] = fusew[o*128 + c];
    }
}

// ---------------------------------------------------------------------------
// f_t[b][n][o] = relu(bn1(sum_c w1[o][c]*x[b][c][n])) ; sq[b][n] = sum_o f^2
// ---------------------------------------------------------------------------
__global__ void __launch_bounds__(256) k_feat0(const float* __restrict__ x,
                                               const float* __restrict__ w1,
                                               const float* __restrict__ sc,
                                               float* __restrict__ ft, float* __restrict__ sq)
{
    const int t = threadIdx.x, lane = t & 63, w = t >> 6;
    const int pid = blockIdx.x*4 + w;
    const int b = pid >> 11, n = pid & (N_-1);
    const float* xb = x + (long)b*6*N_ + n;
    float acc = 0.0f;
    #pragma unroll
    for (int c = 0; c < 6; c++) acc += w1[lane*6 + c] * xb[(long)c*N_];
    float val = fmaxf(sc[SC_S1 + lane]*acc + sc[SC_T1 + lane], 0.0f);
    ft[((long)b*N_ + n)*64 + lane] = val;
    float v2 = val*val;
    #pragma unroll
    for (int s = 1; s < 64; s <<= 1) v2 += __shfl_xor(v2, s);
    if (lane == 0) sq[b*N_ + n] = v2;
}

// ---------------------------------------------------------------------------
// topk_sel3: k smallest (stable first-index ties), index = j*64+lane.
// Per-lane top-2 cache + consumed bitmask; rescan only on second win.
// ---------------------------------------------------------------------------
template<int RPL, int KSEL>
__device__ __forceinline__ void topk_sel3(float (&v)[RPL], int lane, int* __restrict__ out)
{
    unsigned key[RPL];
    #pragma unroll
    for (int j = 0; j < RPL; j++) key[j] = sortable_(v[j]);

    unsigned consumed = 0;
    unsigned m1 = key[0]; int s1 = 0;
    unsigned m2 = 0xFFFFFFFFu; int s2 = 0;
    #pragma unroll
    for (int j = 1; j < RPL; j++) {
        unsigned kk = key[j];
        bool lt1 = kk < m1;
        bool lt2 = kk < m2;
        unsigned nm2 = lt1 ? m1 : (lt2 ? kk : m2);
        int      ns2 = lt1 ? s1 : (lt2 ? j  : s2);
        m1 = lt1 ? kk : m1;
        s1 = lt1 ? j  : s1;
        m2 = nm2; s2 = ns2;
    }

    #pragma unroll 1
    for (int k = 0; k < KSEL; k++) {
        unsigned g = wave_minu(m1);
        unsigned long long cand = __ballot(m1 == g);
        int gi;
        if (__popcll(cand) > 1) {
            int ci = (m1 == g) ? (s1*64 + lane) : 0x7FFFFFFF;
            #pragma unroll
            for (int s = 1; s < 64; s <<= 1) { int o = __shfl_xor(ci, s); ci = o < ci ? o : ci; }
            gi = ci;
        } else {
            int wl = __ffsll((long long)cand) - 1;
            gi = __builtin_amdgcn_readlane(s1, wl) * 64 + wl;
        }
        if (lane == 0) out[k] = gi;
        if (k + 1 < KSEL) {
            bool win = (m1 == g) && (s1*64 + lane == gi);
            if (win) {
                consumed |= 1u << s1;
                m1 = m2; s1 = s2;
                m2 = 0xFFFFFFFFu;
            }
            bool need = win && (m1 == 0xFFFFFFFFu);
            if (__any(need)) {
                if (need) {
                    m1 = 0xFFFFFFFFu; s1 = 0; m2 = 0xFFFFFFFFu; s2 = 0;
                    #pragma unroll
                    for (int j = 0; j < RPL; j++) {
                        unsigned kk = ((consumed >> j) & 1u) ? 0xFFFFFFFFu : key[j];
                        bool lt1 = kk < m1;
                        bool lt2 = kk < m2;
                        unsigned nm2 = lt1 ? m1 : (lt2 ? kk : m2);
                        int      ns2 = lt1 ? s1 : (lt2 ? j  : s2);
                        m1 = lt1 ? kk : m1;
                        s1 = lt1 ? j  : s1;
                        m2 = nm2; s2 = ns2;
                    }
                }
            }
        }
    }
}

// ---------------------------------------------------------------------------
// knn body, global-read refs (L1/L2-resident; no LDS, no barrier).
// ---------------------------------------------------------------------------
template<int NREF, int RPL, int KSEL>
__device__ __forceinline__ void knn_gbody(
    const float* qp, long qBatch, int qsN, int qsD, int NQ,
    const float* rp, long rBatch, long rsN, long rsD,
    int* out, int bid)
{
    const int t = threadIdx.x, lane = t & 63, w = t >> 6;
    const int bpb = NQ / 4;
    const int b = bid / bpb;
    const int qi = (bid % bpb)*4 + w;
    const float* rb = rp + (long)b*rBatch;
    const float* qb = qp + (long)b*qBatch + (long)qi*qsN;
    float qx = qb[0], qy = qb[qsD], qz = qb[2*qsD];
    float sumq = __fadd_rn(__fadd_rn(__fmul_rn(qx,qx), __fmul_rn(qy,qy)), __fmul_rn(qz,qz));
    float v[RPL];
    #pragma unroll
    for (int j = 0; j < RPL; j++) {
        long n = j*64 + lane;
        float rx = rb[n*rsN];
        float ry = rb[n*rsN + rsD];
        float rz = rb[n*rsN + 2*rsD];
        float dot  = __fadd_rn(__fadd_rn(__fmul_rn(qx,rx), __fmul_rn(qy,ry)), __fmul_rn(qz,rz));
        float sumr = __fadd_rn(__fadd_rn(__fmul_rn(rx,rx), __fmul_rn(ry,ry)), __fmul_rn(rz,rz));
        v[j] = __fadd_rn(__fsub_rn(sumq, __fmul_rn(2.0f, dot)), sumr);
    }
    topk_sel3<RPL, KSEL>(v, lane, out + ((long)b*NQ + qi)*KSEL);
}

template<int NREF, int RPL, int KSEL>
__global__ void __launch_bounds__(256, 4) k_knn3d_g(
    const float* __restrict__ qp, long qBatch, int qsN, int qsD, int NQ,
    const float* __restrict__ rp, long rBatch, long rsN, long rsD,
    int* __restrict__ out)
{
    knn_gbody<NREF,RPL,KSEL>(qp, qBatch, qsN, qsD, NQ,
                             rp, rBatch, rsN, rsD, out, blockIdx.x);
}

// ---------------------------------------------------------------------------
// fused dispatch: blocks [0,16) run FPS1->FPS2; blocks [16,16+8192) geo-knn.
// FPS reduce is pure VALU/SALU (DPP ladder + readlane); one LDS merge +
// one barrier per iteration.
// ---------------------------------------------------------------------------
__global__ void __launch_bounds__(256, 4) k_geoknn_fps(
    const float* __restrict__ x, int* __restrict__ idxg,
    int* __restrict__ fps1, float* __restrict__ nx1,
    int* __restrict__ fps2, float* __restrict__ nx2)
{
    __shared__ float  mx2[NP1], my2[NP1], mz2[NP1];   // 6 KiB (FPS1 -> FPS2)
    __shared__ int    sidx1[NP1];                     // 2 KiB
    __shared__ int    sidx2[NP2];                     // 1 KiB
    __shared__ float4 mrgc[2][4];                     // winner coords + value
    __shared__ int    mrgi[2][4];

    if (blockIdx.x < (unsigned)B_) {
        __builtin_amdgcn_s_setprio(3);
        const int t = threadIdx.x, lane = t & 63, wave = t >> 6;
        const int b = blockIdx.x;
        const float* pb = x + (long)b*6*N_;

        // register-resident coords: thread t owns points [8t, 8t+8)
        float px[8], py[8], pz[8], dl[8];
        {
            const float4* a4 = (const float4*)(pb + 8*t);
            const float4* b4 = (const float4*)(pb + N_ + 8*t);
            const float4* c4p = (const float4*)(pb + 2*N_ + 8*t);
            float4 a0 = a4[0], a1 = a4[1];
            float4 b0 = b4[0], b1 = b4[1];
            float4 c0 = c4p[0], c1 = c4p[1];
            px[0]=a0.x; px[1]=a0.y; px[2]=a0.z; px[3]=a0.w;
            px[4]=a1.x; px[5]=a1.y; px[6]=a1.z; px[7]=a1.w;
            py[0]=b0.x; py[1]=b0.y; py[2]=b0.z; py[3]=b0.w;
            py[4]=b1.x; py[5]=b1.y; py[6]=b1.z; py[7]=b1.w;
            pz[0]=c0.x; pz[1]=c0.y; pz[2]=c0.z; pz[3]=c0.w;
            pz[4]=c1.x; pz[5]=c1.y; pz[6]=c1.z; pz[7]=c1.w;
        }
        #pragma unroll
        for (int p = 0; p < 8; p++) dl[p] = 1e10f;

        float cx = pb[0], cy = pb[N_], cz = pb[2*N_];
        int far = 0;

        // ---------------- FPS1: 2048 -> 512 ----------------
        for (int i = 0; i < NP1; i++) {
            if (t == 0) { sidx1[i] = far; mx2[i] = cx; my2[i] = cy; mz2[i] = cz; }
            float bv = -1.0f; int bp = 0;
            #pragma unroll
            for (int p = 0; p < 8; p++) {
                float dx = __fsub_rn(px[p], cx);
                float dy = __fsub_rn(py[p], cy);
                float dz = __fsub_rn(pz[p], cz);
                float d  = __fadd_rn(__fadd_rn(__fmul_rn(dx,dx), __fmul_rn(dy,dy)), __fmul_rn(dz,dz));
                float nd = fminf(dl[p], d);
                dl[p] = nd;
                if (nd > bv) { bv = nd; bp = p; }   // ascending p: first-index ties
            }
            // per-lane candidate coords (independent of reduce; overlaps DPP)
            float wx = px[0], wy = py[0], wz = pz[0];
            #pragma unroll
            for (int p = 1; p < 8; p++) {
                bool c = (bp == p);
                wx = c ? px[p] : wx; wy = c ? py[p] : wy; wz = c ? pz[p] : wz;
            }
            float gm = wave_max64_sgpr(bv);        // pure VALU + readlane
            unsigned long long cand = __ballot(bv == gm);
            int wl = __ffsll((long long)cand) - 1; // lowest lane = lowest orig idx
            int   wbp = __builtin_amdgcn_readlane(bp, wl);
            float sxw = __int_as_float(__builtin_amdgcn_readlane(__float_as_int(wx), wl));
            float syw = __int_as_float(__builtin_amdgcn_readlane(__float_as_int(wy), wl));
            float szw = __int_as_float(__builtin_amdgcn_readlane(__float_as_int(wz), wl));
            int par = i & 1;
            if (lane == 0) {
                mrgc[par][wave] = make_float4(sxw, syw, szw, gm);
                mrgi[par][wave] = (((wave << 6) | wl) << 3) + wbp;
            }
            __syncthreads();
            float4 e0 = mrgc[par][0];
            float fv = e0.w; int fi = mrgi[par][0];
            float ncx = e0.x, ncy = e0.y, ncz = e0.z;
            #pragma unroll
            for (int w2 = 1; w2 < 4; w2++) {
                float4 e2 = mrgc[par][w2]; int i2 = mrgi[par][w2];
                if (e2.w > fv) { fv = e2.w; fi = i2; ncx = e2.x; ncy = e2.y; ncz = e2.z; }
            }
            far = fi; cx = ncx; cy = ncy; cz = ncz;
        }
        __syncthreads();   // mir/sidx1 complete

        int*   f1o = fps1 + b*NP1;
        float* n1o = nx1 + (long)b*NP1*3;
        for (int s = t; s < NP1; s += 256) {
            f1o[s] = sidx1[s];
            n1o[(long)s*3+0] = mx2[s];
            n1o[(long)s*3+1] = my2[s];
            n1o[(long)s*3+2] = mz2[s];
        }

        // ---------------- FPS2: 512 -> 256 (2 pts/thread from mir) ----------
        {
            const int n0 = t << 1;
            float ax = mx2[n0],   ay = my2[n0],   az = mz2[n0];
            float bx = mx2[n0+1], by = my2[n0+1], bz = mz2[n0+1];
            float dl0 = 1e10f, dl1 = 1e10f;
            int far2 = 0;
            float c2x = mx2[0], c2y = my2[0], c2z = mz2[0];
            for (int i = 0; i < NP2; i++) {
                if (t == 0) sidx2[i] = far2;
                float dx = __fsub_rn(ax, c2x), dy = __fsub_rn(ay, c2y), dz = __fsub_rn(az, c2z);
                float d0 = __fadd_rn(__fadd_rn(__fmul_rn(dx,dx), __fmul_rn(dy,dy)), __fmul_rn(dz,dz));
                dx = __fsub_rn(bx, c2x); dy = __fsub_rn(by, c2y); dz = __fsub_rn(bz, c2z);
                float d1 = __fadd_rn(__fadd_rn(__fmul_rn(dx,dx), __fmul_rn(dy,dy)), __fmul_rn(dz,dz));
                dl0 = fminf(dl0, d0);
                dl1 = fminf(dl1, d1);
                float bv = dl0; int bp = 0;
                if (dl1 > bv) { bv = dl1; bp = 1; }
                float wx = bp ? bx : ax, wy = bp ? by : ay, wz = bp ? bz : az;
                float gm = wave_max64_sgpr(bv);
                unsigned long long cand = __ballot(bv == gm);
                int wl = __ffsll((long long)cand) - 1;
                int   wbp = __builtin_amdgcn_readlane(bp, wl);
                float sxw = __int_as_float(__builtin_amdgcn_readlane(__float_as_int(wx), wl));
                float syw = __int_as_float(__builtin_amdgcn_readlane(__float_as_int(wy), wl));
                float szw = __int_as_float(__builtin_amdgcn_readlane(__float_as_int(wz), wl));
                int par = i & 1;
                if (lane == 0) {
                    mrgc[par][wave] = make_float4(sxw, syw, szw, gm);
                    mrgi[par][wave] = (((wave << 6) | wl) << 1) + wbp;
                }
                __syncthreads();
                float4 e0 = mrgc[par][0];
                float fv = e0.w; int fi = mrgi[par][0];
                float ncx = e0.x, ncy = e0.y, ncz = e0.z;
                #pragma unroll
                for (int w2 = 1; w2 < 4; w2++) {
                    float4 e2 = mrgc[par][w2]; int i2 = mrgi[par][w2];
                    if (e2.w > fv) { fv = e2.w; fi = i2; ncx = e2.x; ncy = e2.y; ncz = e2.z; }
                }
                far2 = fi; c2x = ncx; c2y = ncy; c2z = ncz;
            }
        }
        __syncthreads();   // sidx2 visible

        int*   f2o = fps2 + b*NP2;
        float* n2o = nx2 + (long)b*NP2*3;
        for (int s = t; s < NP2; s += 256) {
            int j = sidx2[s];
            f2o[s] = j;
            n2o[(long)s*3+0] = mx2[j];
            n2o[(long)s*3+1] = my2[j];
            n2o[(long)s*3+2] = mz2[j];
        }
        __builtin_amdgcn_s_setprio(0);
        return;
    }
    knn_gbody<N_,32,KG>(x, (long)6*N_, 1, N_, N_,
                        x, (long)6*N_, 1, N_, idxg, blockIdx.x - B_);
}

// ---------------------------------------------------------------------------
// top-20 selection from a precomputed distance-chunk row (feature knn)
// ---------------------------------------------------------------------------
__global__ void __launch_bounds__(256, 4) k_selectD(const float* __restrict__ D, int qbase,
                                                    int* __restrict__ out)
{
    const int t = threadIdx.x, lane = t & 63, w = t >> 6;
    const int r = blockIdx.x*4 + w;
    const int b = r / CHQ, qi = r % CHQ;
    const float* row = D + ((long)b*CHQ + qi) * N_;
    float v[32];
    #pragma unroll
    for (int j = 0; j < 32; j++) v[j] = row[j*64 + lane];
    topk_sel3<32, KG>(v, lane, out + ((long)b*N_ + qbase + qi)*KG);
}

// ---------------------------------------------------------------------------
// generic 64x64-tile fp32 GEMM: C[b] = A[b] * Bw^T with epilogues.
// ---------------------------------------------------------------------------
__global__ void __launch_bounds__(256) k_gemm(
    const float* __restrict__ A, long aBatch, int aRow,
    const float* __restrict__ Bw, long bBatch, int K,
    float* __restrict__ C, long cBatch, int cRow, int cCol0,
    int act, const float* __restrict__ sv, const float* __restrict__ tv,
    const float* __restrict__ sqv, int sqBatch, int sqQBase,
    int epi)
{
    __shared__ float As[64][68];
    __shared__ float Bs[64][68];
    const int b  = blockIdx.z;
    const int ib = blockIdx.x * 64;
    const int jb = blockIdx.y * 64;
    const int t  = threadIdx.x;
    const int tx = t & 15, ty = t >> 4;
    const float* Ab = A + (long)b * aBatch;
    const float* Bb = Bw + (long)b * bBatch;
    float acc[4][4];
    #pragma unroll
    for (int i = 0; i < 4; i++)
        #pragma unroll
        for (int j = 0; j < 4; j++) acc[i][j] = 0.0f;

    for (int kb = 0; kb < K; kb += 64) {
        #pragma unroll
        for (int m = 0; m < 4; m++) {
            int li = t + m*256; int r = li >> 4; int c4 = li & 15;
            float4 av = *(const float4*)(Ab + (long)(ib + r)*aRow + kb + c4*4);
            As[c4*4+0][r] = av.x; As[c4*4+1][r] = av.y;
            As[c4*4+2][r] = av.z; As[c4*4+3][r] = av.w;
            float4 bv = *(const float4*)(Bb + (long)(jb + r)*K + kb + c4*4);
            Bs[c4*4+0][r] = bv.x; Bs[c4*4+1][r] = bv.y;
            Bs[c4*4+2][r] = bv.z; Bs[c4*4+3][r] = bv.w;
        }
        __syncthreads();
        #pragma unroll 4
        for (int k = 0; k < 64; k++) {
            float4 a  = *(const float4*)&As[k][ty*4];
            float4 b4 = *(const float4*)&Bs[k][tx*4];
            acc[0][0] += a.x*b4.x; acc[0][1] += a.x*b4.y; acc[0][2] += a.x*b4.z; acc[0][3] += a.x*b4.w;
            acc[1][0] += a.y*b4.x; acc[1][1] += a.y*b4.y; acc[1][2] += a.y*b4.z; acc[1][3] += a.y*b4.w;
            acc[2][0] += a.z*b4.x; acc[2][1] += a.z*b4.y; acc[2][2] += a.z*b4.z; acc[2][3] += a.z*b4.w;
            acc[3][0] += a.w*b4.x; acc[3][1] += a.w*b4.y; acc[3][2] += a.w*b4.z; acc[3][3] += a.w*b4.w;
        }
        __syncthreads();
    }

    const int i0 = ib + ty*4;
    const int j0 = jb + tx*4;
    if (epi == 1) {
        #pragma unroll
        for (int ii = 0; ii < 4; ii++) {
            float sqq = sqv[(long)b*sqBatch + sqQBase + i0 + ii];
            #pragma unroll
            for (int jj = 0; jj < 4; jj++) {
                int r = j0 + jj;
                float sqr = sqv[(long)b*sqBatch + r];
                C[(long)b*cBatch + (long)(i0+ii)*cRow + r] = (sqq - 2.0f*acc[ii][jj]) + sqr;
            }
        }
    } else if (epi == 2) {
        #pragma unroll
        for (int ii = 0; ii < 4; ii++)
            #pragma unroll
            for (int jj = 0; jj < 4; jj++) {
                int j = j0 + jj;
                float vv = lrelu_(sv[j]*acc[ii][jj] + tv[j]);
                C[(long)b*cBatch + (long)j*cRow + (i0+ii)] = vv;
            }
    } else {
        #pragma unroll
        for (int ii = 0; ii < 4; ii++)
            #pragma unroll
            for (int jj = 0; jj < 4; jj++) {
                int j = j0 + jj;
                float vv = acc[ii][jj];
                if (act == 1) vv = fmaxf(sv[j]*vv + tv[j], 0.0f);
                else if (act == 2) vv = lrelu_(sv[j]*vv + tv[j]);
                C[(long)b*cBatch + (long)(i0+ii)*cRow + cCol0 + j] = vv;
            }
    }
}

// ---------------------------------------------------------------------------
// edge gather-max (geo + feat) + fuse GEMM + bn/lrelu -> out_feat_t (B,N,64)
// ---------------------------------------------------------------------------
__global__ void __launch_bounds__(256) k_edgefuse(
    const float* __restrict__ P, const int* __restrict__ idxg, const int* __restrict__ idxf,
    const float* __restrict__ wft, const float* __restrict__ sc,
    float* __restrict__ outf)
{
    __shared__ float wt[128*64];
    __shared__ float fused[4][128];
    const int t = threadIdx.x, lane = t & 63, w = t >> 6;
    for (int i = t; i < 128*64; i += 256) wt[i] = wft[i];
    const int pid = blockIdx.x*4 + w;
    const int b = pid >> 11, n = pid & (N_-1);
    const float* Prow = P + ((long)b*N_ + n)*256;
    const int* ig  = idxg + ((long)b*N_ + n)*KG;
    const int* ifx = idxf + ((long)b*N_ + n)*KG;
    float gmax = -FLT_MAX, hmax = -FLT_MAX;
    for (int k = 0; k < KG; k++) {
        int idg = ig[k];
        gmax = fmaxf(gmax, P[((long)b*N_ + idg)*256 + lane]);
        int idf = ifx[k];
        hmax = fmaxf(hmax, P[((long)b*N_ + idf)*256 + 128 + lane]);
    }
    float glin = gmax - Prow[lane]       + Prow[64 + lane];
    float hlin = hmax - Prow[128 + lane] + Prow[192 + lane];
    float gv = lrelu_(sc[SC_SGEO + lane]*glin + sc[SC_TGEO + lane]);
    float hv = lrelu_(sc[SC_SFEAT + lane]*hlin + sc[SC_TFEAT + lane]);
    fused[w][lane]      = gv;
    fused[w][64 + lane] = hv;
    __syncthreads();
    float acc = 0.0f;
    #pragma unroll 8
    for (int c4 = 0; c4 < 32; c4++) {
        float4 f = *(const float4*)&fused[w][c4*4];
        acc += f.x * wt[(c4*4+0)*64 + lane];
        acc += f.y * wt[(c4*4+1)*64 + lane];
        acc += f.z * wt[(c4*4+2)*64 + lane];
        acc += f.w * wt[(c4*4+3)*64 + lane];
    }
    float ov = lrelu_(sc[SC_SFUSE + lane]*acc + sc[SC_TFUSE + lane]);
    outf[((long)b*N_ + n)*64 + lane] = ov;
}

// ---------------------------------------------------------------------------
// local_op gather-max: out[b,s,o] = relu(bn(max_k Q[idx[k]][o] + Qc[crow][CO+o]))
// ---------------------------------------------------------------------------
template<int QN, int ROWW, int CO, int MROWS, int SO>
__global__ void __launch_bounds__(256) k_gathermax(
    const float* __restrict__ Q, const int* __restrict__ knn, const int* __restrict__ fpsi,
    const float* __restrict__ sv, const float* __restrict__ tv,
    float* __restrict__ outp, int outRow)
{
    const int t = threadIdx.x, lane = t & 63, w = t >> 6;
    const int pid = blockIdx.x*4 + w;
    const int b = pid / SO, s = pid % SO;
    const int* ix = knn + ((long)b*SO + s)*NSAMP;
    float mx[QN];
    #pragma unroll
    for (int q = 0; q < QN; q++) mx[q] = -FLT_MAX;
    for (int k = 0; k < NSAMP; k++) {
        int id = ix[k];
        const float* r = Q + ((long)b*MROWS + id)*ROWW;
        #pragma unroll
        for (int q = 0; q < QN; q++) mx[q] = fmaxf(mx[q], r[lane + 64*q]);
    }
    int crow = fpsi[b*SO + s];
    const float* cr = Q + ((long)b*MROWS + crow)*ROWW + CO;
    #pragma unroll
    for (int q = 0; q < QN; q++) {
        int o = lane + 64*q;
        float lin = mx[q] + cr[o];
        float val = fmaxf(sv[o]*lin + tv[o], 0.0f);
        outp[((long)b*SO + s)*outRow + o] = val;
    }
}

// ---------------------------------------------------------------------------
extern "C" void kernel_launch(void* const* d_in, const int* in_sizes, int n_in,
                              void* d_out, int out_size, void* d_ws, size_t ws_size,
                              hipStream_t stream)
{
    const float* x      = (const float*)d_in[0];
    const float* w1     = (const float*)d_in[1];
    const float* bn1    = (const float*)d_in[2];
    const float* w2     = (const float*)d_in[3];
    const float* bn2    = (const float*)d_in[4];
    const float* geow   = (const float*)d_in[5];
    const float* geobn  = (const float*)d_in[6];
    const float* featw  = (const float*)d_in[7];
    const float* featbn = (const float*)d_in[8];
    const float* fusew  = (const float*)d_in[9];
    const float* fusebn = (const float*)d_in[10];
    const float* gl0w   = (const float*)d_in[11];
    const float* gl0bn  = (const float*)d_in[12];
    const float* gl1w   = (const float*)d_in[13];
    const float* gl1bn  = (const float*)d_in[14];
    const float* wf     = (const float*)d_in[15];
    const float* bnfp   = (const float*)d_in[16];

    float* ws  = (float*)d_ws;
    float* out = (float*)d_out;

    float* FT   = ws + OFF_FT;
    float* SQ   = ws + OFF_SQ;
    float* BIG  = ws + OFF_BIG;
    int*   IDXG = (int*)(ws + OFF_IDXG);
    int*   IDXF = (int*)(ws + OFF_IDXF);
    float* OUTF = ws + OFF_OUTF;
    int*   FPS1 = (int*)(ws + OFF_FPS1);
    float* NX1  = ws + OFF_NX1;
    int*   IDX1 = (int*)(ws + OFF_IDX1);
    float* F0T  = ws + OFF_F0T;
    int*   FPS2 = (int*)(ws + OFF_FPS2);
    float* NX2  = ws + OFF_NX2;
    int*   IDX2 = (int*)(ws + OFF_IDX2);
    float* Q1B  = ws + OFF_Q1;
    float* V    = ws + OFF_V;
    float* WPP  = ws + OFF_WPP;
    float* WPQ0 = ws + OFF_WPQ0;
    float* WPQ1 = ws + OFF_WPQ1;
    float* WFT  = ws + OFF_WFT;
    float* SC   = ws + OFF_SC;
    const float* nfp = nullptr;

    hipLaunchKernelGGL(k_prep, dim3(64), dim3(256), 0, stream,
        bn1, bn2, geow, geobn, featw, featbn, fusew, fusebn, gl0w, gl0bn, gl1w, gl1bn, bnfp, ws);

    hipLaunchKernelGGL(k_feat0, dim3(B_*N_/4), dim3(256), 0, stream, x, w1, SC, FT, SQ);

    // fused: FPS1->FPS2 chain (16 leading blocks) + geo knn (8192 blocks)
    hipLaunchKernelGGL(k_geoknn_fps, dim3(B_ + B_*(N_/4)), dim3(256), 0, stream,
        x, IDXG, FPS1, NX1, FPS2, NX2);

    // feature knn: distance chunks + selection
    for (int ci = 0; ci < N_/CHQ; ci++) {
        int qbase = ci*CHQ;
        hipLaunchKernelGGL(k_gemm, dim3(CHQ/64, N_/64, B_), dim3(256), 0, stream,
            FT + (long)qbase*64, (long)N_*64, 64,
            FT, (long)N_*64, 64,
            BIG, (long)CHQ*N_, N_, 0,
            0, nfp, nfp, SQ, N_, qbase, 1);
        hipLaunchKernelGGL(k_selectD, dim3(B_*CHQ/4), dim3(256), 0, stream, BIG, qbase, IDXF);
    }

    // P projection (B,N,256) into BIG
    hipLaunchKernelGGL(k_gemm, dim3(N_/64, 256/64, B_), dim3(256), 0, stream,
        FT, (long)N_*64, 64, WPP, (long)0, 64,
        BIG, (long)N_*256, 256, 0, 0, nfp, nfp, nfp, 0, 0, 0);

    hipLaunchKernelGGL(k_edgefuse, dim3(B_*N_/4), dim3(256), 0, stream,
        BIG, IDXG, IDXF, WFT, SC, OUTF);

    // grouping knn 1 (queries = NX1 from fused FPS), global-read refs
    hipLaunchKernelGGL((k_knn3d_g<2048,32,32>), dim3(B_*(NP1/4)), dim3(256), 0, stream,
        NX1, (long)NP1*3, 3, 1, NP1, x, (long)6*N_, (long)1, (long)N_, IDX1);

    // Q0 projection (B,N,256) into BIG (P is dead now)
    hipLaunchKernelGGL(k_gemm, dim3(N_/64, 256/64, B_), dim3(256), 0, stream,
        OUTF, (long)N_*64, 64, WPQ0, (long)0, 64,
        BIG, (long)N_*256, 256, 0, 0, nfp, nfp, nfp, 0, 0, 0);

    hipLaunchKernelGGL((k_gathermax<2,256,128,2048,512>), dim3(B_*NP1/4), dim3(256), 0, stream,
        BIG, IDX1, FPS1, SC + SC_SGL0, SC + SC_TGL0, F0T, 128);

    // grouping knn 2 (queries = NX2), global-read refs
    hipLaunchKernelGGL((k_knn3d_g<512,8,32>), dim3(B_*(NP2/4)), dim3(256), 0, stream,
        NX2, (long)NP2*3, 3, 1, NP2, NX1, (long)NP1*3, (long)3, (long)1, IDX2);

    // Q1 projection (B,512,512)
    hipLaunchKernelGGL(k_gemm, dim3(NP1/64, 512/64, B_), dim3(256), 0, stream,
        F0T, (long)NP1*128, 128, WPQ1, (long)0, 128,
        Q1B, (long)NP1*512, 512, 0, 0, nfp, nfp, nfp, 0, 0, 0);

    hipLaunchKernelGGL((k_gathermax<4,512,256,512,256>), dim3(B_*NP2/4), dim3(256), 0, stream,
        Q1B, IDX2, FPS2, SC + SC_SGL1, SC + SC_TGL1, V, 1280);

    // x_skip -> V[:, :, 256:1280]  (A = f_t rows at stride 8 points)
    hipLaunchKernelGGL(k_gemm, dim3(NP2/64, 1024/64, B_), dim3(256), 0, stream,
        FT, (long)N_*64, 512, w2, (long)0, 64,
        V, (long)NP2*1280, 1280, 256, 1, SC + SC_S2, SC + SC_T2, nfp, 0, 0, 0);

    // final (B,512,256) = lrelu(bnf(wf . V^T)), transposed store
    hipLaunchKernelGGL(k_gemm, dim3(NP2/64, 512/64, B_), dim3(256), 0, stream,
        V, (long)NP2*1280, 1280, wf, (long)0, 1280,
        out, (long)512*256, 256, 0, 2, SC + SC_SF, SC + SC_TF, nfp, 0, 0, 2);

    (void)in_sizes; (void)n_in; (void)out_size; (void)ws_size;
}